// Round 17
// baseline (442.220 us; speedup 1.0000x reference)
//
#include <hip/hip_runtime.h>
#include <stdint.h>

#define B 8
#define S 128
#define D 512
#define NIN 1024
#define NOUT 1024
#define T 32

typedef __attribute__((ext_vector_type(8))) short short8;
typedef __attribute__((ext_vector_type(4))) float floatx4;

// direct global->LDS 16B copy (no VGPR round-trip, counted by vmcnt)
__device__ __forceinline__ void gload_lds16(const void* g, void* l)
{
    __builtin_amdgcn_global_load_lds(
        (const __attribute__((address_space(1))) unsigned int*)g,
        (__attribute__((address_space(3))) unsigned int*)l,
        16, 0, 0);
}

// ---------------------------------------------------------------------------
// Generic fp32 tiled GEMM: C[M,N] = maybe_relu(A[M,K] @ Bm[K,N] + bias[N])
// Register prefetch of the next k-slab before the FMA block (verified R2).
// ---------------------------------------------------------------------------
__global__ __launch_bounds__(256) void k_gemm(const float* __restrict__ A,
                                              const float* __restrict__ Bm,
                                              const float* __restrict__ bias,
                                              float* __restrict__ C,
                                              int M, int N, int K, int relu)
{
    __shared__ float As[16][64];
    __shared__ float Bs[16][64];
    const int tid = threadIdx.x;
    const int bx = blockIdx.x, by = blockIdx.y;
    const int tx = tid & 15, ty = tid >> 4;
    const int ar = tid >> 2, ak = (tid & 3) << 2;
    const int bk = tid >> 4, bc = (tid & 15) << 2;
    float acc[4][4] = {{0.f,0.f,0.f,0.f},{0.f,0.f,0.f,0.f},
                       {0.f,0.f,0.f,0.f},{0.f,0.f,0.f,0.f}};
    float4 a4 = *(const float4*)(A + (size_t)(by*64 + ar)*K + ak);
    float4 b4 = *(const float4*)(Bm + (size_t)bk*N + bx*64 + bc);
    for (int k0 = 0; k0 < K; k0 += 16) {
        __syncthreads();
        As[ak+0][ar] = a4.x; As[ak+1][ar] = a4.y;
        As[ak+2][ar] = a4.z; As[ak+3][ar] = a4.w;
        *(float4*)&Bs[bk][bc] = b4;
        float4 na, nb;
        const bool has = (k0 + 16 < K);
        if (has) {
            na = *(const float4*)(A + (size_t)(by*64 + ar)*K + k0 + 16 + ak);
            nb = *(const float4*)(Bm + (size_t)(k0 + 16 + bk)*N + bx*64 + bc);
        }
        __syncthreads();
        #pragma unroll
        for (int kk = 0; kk < 16; ++kk) {
            float4 av = *(const float4*)&As[kk][ty << 2];
            float4 bv = *(const float4*)&Bs[kk][tx << 2];
            acc[0][0] = fmaf(av.x, bv.x, acc[0][0]);
            acc[0][1] = fmaf(av.x, bv.y, acc[0][1]);
            acc[0][2] = fmaf(av.x, bv.z, acc[0][2]);
            acc[0][3] = fmaf(av.x, bv.w, acc[0][3]);
            acc[1][0] = fmaf(av.y, bv.x, acc[1][0]);
            acc[1][1] = fmaf(av.y, bv.y, acc[1][1]);
            acc[1][2] = fmaf(av.y, bv.z, acc[1][2]);
            acc[1][3] = fmaf(av.y, bv.w, acc[1][3]);
            acc[2][0] = fmaf(av.z, bv.x, acc[2][0]);
            acc[2][1] = fmaf(av.z, bv.y, acc[2][1]);
            acc[2][2] = fmaf(av.z, bv.z, acc[2][2]);
            acc[2][3] = fmaf(av.z, bv.w, acc[2][3]);
            acc[3][0] = fmaf(av.w, bv.x, acc[3][0]);
            acc[3][1] = fmaf(av.w, bv.y, acc[3][1]);
            acc[3][2] = fmaf(av.w, bv.z, acc[3][2]);
            acc[3][3] = fmaf(av.w, bv.w, acc[3][3]);
        }
        if (has) { a4 = na; b4 = nb; }
    }
    const int row0 = by*64 + (ty << 2), col0 = bx*64 + (tx << 2);
    float4 bb = *(const float4*)(bias + col0);
    #pragma unroll
    for (int i = 0; i < 4; ++i) {
        float4 o;
        o.x = acc[i][0] + bb.x; o.y = acc[i][1] + bb.y;
        o.z = acc[i][2] + bb.z; o.w = acc[i][3] + bb.w;
        if (relu) {
            o.x = fmaxf(o.x, 0.f); o.y = fmaxf(o.y, 0.f);
            o.z = fmaxf(o.z, 0.f); o.w = fmaxf(o.w, 0.f);
        }
        *(float4*)(C + (size_t)(row0 + i)*N + col0) = o;
    }
}

// ---------------------------------------------------------------------------
// Input LIF phase A — R3 split form + depth-2 prefetch (R15-measured config).
// One chain/thread, 8192 threads over 128 CUs. Arithmetic identical.
// ---------------------------------------------------------------------------
__global__ __launch_bounds__(64) void k_lif_inA(const float* __restrict__ snn,
                                                unsigned int* __restrict__ sbits,
                                                unsigned int* __restrict__ counters)
{
    const int tid = blockIdx.x * 64 + threadIdx.x;   // 0..8191
    const int b = tid >> 10, n = tid & (NIN - 1);
    const float* cur = snn + (size_t)(b * S) * NIN + n;
    float v = 0.f;
    int cnt = 0;
    float I   = cur[0];
    float In1 = (1 < S) ? cur[(size_t)1 * NIN] : 0.f;
    for (int s = 0; s < S; ++s) {
        const float In2 = (s + 2 < S) ? cur[(size_t)(s + 2) * NIN] : 0.f;
        unsigned int bits = 0u;
        #pragma unroll
        for (int t = 0; t < T; ++t) {
            v = __fadd_rn(__fmul_rn(0.9f, v), I);
            const bool sp = (v >= 1.0f);
            v = sp ? (v - 1.0f) : v;
            bits |= (sp ? 1u : 0u) << t;
        }
        sbits[(size_t)(b * S + s) * NIN + n] = bits;
        cnt += __popc(bits);
        I = In1; In1 = In2;
    }
    atomicAdd(counters, (unsigned int)cnt);
}

// ---------------------------------------------------------------------------
// Input LIF phase B — R3-exact: parallel rebuild of the u64 ballot masks.
// ---------------------------------------------------------------------------
__global__ __launch_bounds__(256) void k_lif_inB(const unsigned int* __restrict__ sbits,
                                                 unsigned long long* __restrict__ masks)
{
    const int bs = blockIdx.x;                 // b*S+s
    const int w = threadIdx.x >> 6, lane = threadIdx.x & 63;
    #pragma unroll
    for (int i = 0; i < 4; ++i) {
        const int wq = w * 4 + i;
        const unsigned int bits = sbits[(size_t)bs * NIN + wq * 64 + lane];
        #pragma unroll
        for (int t = 0; t < T; ++t) {
            const unsigned long long m = __ballot((bits >> t) & 1u);
            if (lane == 0)
                masks[((size_t)bs * T + t) * 16 + wq] = m;
        }
    }
}

// ---------------------------------------------------------------------------
// Prep: transpose W_conn [k][n] -> WcT [n][k] and split fp32 = bf16_hi+bf16_lo
// ---------------------------------------------------------------------------
__global__ __launch_bounds__(256) void k_prep(const float* __restrict__ Wc,
                                              unsigned short* __restrict__ WhT,
                                              unsigned short* __restrict__ WlT)
{
    __shared__ float tile[64][65];
    const int k0 = blockIdx.x * 64, n0 = blockIdx.y * 64;
    const int tx = threadIdx.x & 63, ty = threadIdx.x >> 6;
    #pragma unroll
    for (int p = 0; p < 16; ++p) {
        const int kl = p*4 + ty;
        tile[kl][tx] = Wc[(size_t)(k0 + kl) * NOUT + n0 + tx];
    }
    __syncthreads();
    #pragma unroll
    for (int p = 0; p < 16; ++p) {
        const int nl = p*4 + ty;
        const float w = tile[tx][nl];
        const unsigned int u  = __float_as_uint(w);
        const unsigned int hb = (u + 0x7FFFu + ((u >> 16) & 1u)) & 0xFFFF0000u; // bf16 RNE
        const float hif = __uint_as_float(hb);
        const float lo  = w - hif;                                             // exact
        const unsigned int ul = __float_as_uint(lo);
        const unsigned short lob = (unsigned short)((ul + 0x7FFFu + ((ul >> 16) & 1u)) >> 16);
        WhT[(size_t)(n0 + nl) * NIN + k0 + tx] = (unsigned short)(hb >> 16);
        WlT[(size_t)(n0 + nl) * NIN + k0 + tx] = lob;
    }
}

// ---------------------------------------------------------------------------
// Spike GEMM via MFMA. R16 change: A-fragment built IN REGISTERS from the
// mask byte instead of the LDS LUT. R15 counters: B-frag reads are
// conflict-free by swizzle design, so the 1.64e7 conflict cycles (26.7 us
// = 22% of the dispatch) must come from the data-random lut[byte] reads.
// Each LUT entry is trivially computable: dword_i = (b0?0x3F80:0)|
// (b1?0x3F800000:0) — exactly the LUT init expression, so MFMA operands
// are bit-identical. Moves work from the conflict-prone LDS pipe to the
// 26%-busy VALU pipe (co-issues with MFMA, m114); LDS reads drop 1/3.
// Everything else is the R3/R15-measured structure (BK=128, f=4,
// double-buffered gload_lds, both-sides XOR swizzle).
// ---------------------------------------------------------------------------
__global__ __launch_bounds__(256) void k_conn_mfma(const uint4* __restrict__ masks128,
                                                   const unsigned short* __restrict__ WhT,
                                                   const unsigned short* __restrict__ WlT,
                                                   float* __restrict__ Iout,
                                                   int s0, int P)
{
    __shared__ unsigned short Bsm[2][2][64][128];   // [buf][mat][col][k] 64 KB

    const int tid = threadIdx.x;
    const int w = tid >> 6, lane = tid & 63;
    const int r16 = lane & 15, q = lane >> 4;
    const int PT = P * T;
    const int rowblk = blockIdx.x * 256 + w * 64;
    const int cb = blockIdx.y * 64;

    const uint4* aptr[4];
    #pragma unroll
    for (int f = 0; f < 4; ++f) {
        const int r = rowblk + f*16 + r16;
        const int b = r / PT;
        const int within = r - b * PT;
        const int grow = (b * S + s0) * T + within;
        aptr[f] = masks128 + (size_t)grow * 8;
    }

    // per-thread staging sources (8 slots), with source-side XOR swizzle
    const unsigned short* stg_src[8];
    #pragma unroll
    for (int i = 0; i < 8; ++i) {
        const int flat = tid + i * 256;          // [mat(1)|col(6)|k16(4)]
        const int mat  = flat >> 10;
        const int col  = (flat >> 4) & 63;
        const int k16  = flat & 15;
        const int k16s = k16 ^ (col & 7);        // inverse swizzle on source
        stg_src[i] = (mat ? WlT : WhT) + (size_t)(cb + col) * NIN + k16s * 8;
    }

#define STAGE(BUF, CH) do {                                                   \
        char* dst0 = (char*)(&Bsm[BUF][0][0][0]) + (size_t)tid * 16;          \
        _Pragma("unroll")                                                     \
        for (int i_ = 0; i_ < 8; ++i_)                                        \
            gload_lds16(stg_src[i_] + (CH) * 128, dst0 + i_ * 4096);          \
    } while (0)

#define COMPUTE(BUF, AW) do {                                                 \
        _Pragma("unroll")                                                     \
        for (int kc = 0; kc < 4; ++kc) {                                      \
            short8 bh[4], bl[4];                                              \
            const int kread = ((kc*4 + q) ^ (r16 & 7)) * 8;                   \
            _Pragma("unroll")                                                 \
            for (int c = 0; c < 4; ++c) {                                     \
                bh[c] = *(const short8*)&Bsm[BUF][0][c*16 + r16][kread];      \
                bl[c] = *(const short8*)&Bsm[BUF][1][c*16 + r16][kread];      \
            }                                                                 \
            _Pragma("unroll")                                                 \
            for (int f = 0; f < 4; ++f) {                                     \
                const unsigned int word = (kc == 0) ? AW[f].x                 \
                                        : (kc == 1) ? AW[f].y                 \
                                        : (kc == 2) ? AW[f].z : AW[f].w;      \
                const unsigned int byte = (word >> (q * 8)) & 0xFFu;          \
                uint4 av_;                                                    \
                av_.x = ((byte &   1u) ? 0x3F80u : 0u)                        \
                      | ((byte &   2u) ? 0x3F800000u : 0u);                   \
                av_.y = ((byte &   4u) ? 0x3F80u : 0u)                        \
                      | ((byte &   8u) ? 0x3F800000u : 0u);                   \
                av_.z = ((byte &  16u) ? 0x3F80u : 0u)                        \
                      | ((byte &  32u) ? 0x3F800000u : 0u);                   \
                av_.w = ((byte &  64u) ? 0x3F80u : 0u)                        \
                      | ((byte & 128u) ? 0x3F800000u : 0u);                   \
                const short8 a = *(const short8*)&av_;                        \
                _Pragma("unroll")                                             \
                for (int c = 0; c < 4; ++c) {                                 \
                    acc[f][c] = __builtin_amdgcn_mfma_f32_16x16x32_bf16(      \
                                    a, bh[c], acc[f][c], 0, 0, 0);            \
                    acc[f][c] = __builtin_amdgcn_mfma_f32_16x16x32_bf16(      \
                                    a, bl[c], acc[f][c], 0, 0, 0);            \
                }                                                             \
            }                                                                 \
        }                                                                     \
    } while (0)

    floatx4 acc[4][4];
    #pragma unroll
    for (int f = 0; f < 4; ++f)
        #pragma unroll
        for (int c = 0; c < 4; ++c)
            acc[f][c] = (floatx4){0.f, 0.f, 0.f, 0.f};

    uint4 awA[4], awB[4];
    #pragma unroll
    for (int f = 0; f < 4; ++f) awA[f] = aptr[f][0];
    STAGE(0, 0);
    __syncthreads();            // drains stage(0)

    #pragma unroll 1
    for (int ch = 0; ch < 8; ch += 2) {
        // phase A: buf0 holds chunk ch; prefetch ch+1 into buf1
        STAGE(1, ch + 1);
        #pragma unroll
        for (int f = 0; f < 4; ++f) awB[f] = aptr[f][ch + 1];
        COMPUTE(0, awA);
        __syncthreads();        // stage(ch+1) done (hidden under MFMAs)

        // phase B: buf1 holds chunk ch+1; prefetch ch+2 into buf0
        if (ch + 2 < 8) {
            STAGE(0, ch + 2);
            #pragma unroll
            for (int f = 0; f < 4; ++f) awA[f] = aptr[f][ch + 2];
        }
        COMPUTE(1, awB);
        __syncthreads();
    }
#undef STAGE
#undef COMPUTE

    #pragma unroll
    for (int f = 0; f < 4; ++f) {
        const int row = rowblk + f*16 + q*4;
        #pragma unroll
        for (int c = 0; c < 4; ++c) {
            const int col = cb + c*16 + r16;
            #pragma unroll
            for (int i = 0; i < 4; ++i)
                Iout[(size_t)(row + i) * NOUT + col] = acc[f][c][i];
        }
    }
}

// ---------------------------------------------------------------------------
// Output-population LIF, 128x64 grid (R15-measured). R16 change: prefetch
// depth 1 -> 2 (cur/n1/n2 rotation). The 32-load batch per position needs
// ~2 compute-phases of L3 latency to land; depth-2 keeps ~64 loads in
// flight. +32 VGPR is free at 1 wave/SIMD. Arithmetic identical.
// ---------------------------------------------------------------------------
__global__ __launch_bounds__(64) void k_lif_out(const float* __restrict__ Iout,
                                                float* __restrict__ vstate,
                                                float* __restrict__ sacc_out,
                                                unsigned int* __restrict__ counters,
                                                int s0, int P, int init)
{
    const int tid = blockIdx.x * 64 + threadIdx.x;
    const int b = tid >> 10, n = tid & (NOUT - 1);
    const int Tc = P * T;
    float v = init ? 0.f : vstate[tid];
    const float* ip = Iout + (size_t)b * Tc * NOUT + n;
    int cnt = 0;

    float cur[T], n1[T];
    #pragma unroll
    for (int t = 0; t < T; ++t) cur[t] = ip[(size_t)t * NOUT];
    if (1 < P) {
        const float* ip1 = ip + (size_t)T * NOUT;
        #pragma unroll
        for (int t = 0; t < T; ++t) n1[t] = ip1[(size_t)t * NOUT];
    }

    for (int sl = 0; sl < P; ++sl) {
        float n2[T];
        const bool has2 = (sl + 2 < P);
        if (has2) {
            const float* ip2 = ip + (size_t)(sl + 2) * T * NOUT;
            #pragma unroll
            for (int t = 0; t < T; ++t) n2[t] = ip2[(size_t)t * NOUT];
        }
        float sacc = 0.f;
        #pragma unroll
        for (int t = 0; t < T; ++t) {
            v = __fadd_rn(__fmul_rn(0.9f, v), cur[t]);
            const bool sp = (v >= 1.0f);
            v = sp ? (v - 1.0f) : v;
            sacc += sp ? 1.f : 0.f;
            cnt += sp ? 1 : 0;
        }
        sacc_out[(size_t)(b*S + s0 + sl) * NOUT + n] = sacc;
        if (sl + 1 < P) {
            #pragma unroll
            for (int t = 0; t < T; ++t) cur[t] = n1[t];
        }
        if (has2) {
            #pragma unroll
            for (int t = 0; t < T; ++t) n1[t] = n2[t];
        }
    }
    vstate[tid] = v;
    atomicAdd(counters + 1, (unsigned int)cnt);
}

__global__ void k_init(unsigned int* c)
{
    if (threadIdx.x < 2) c[threadIdx.x] = 0u;
}

__global__ void k_rate(const unsigned int* __restrict__ c, float* __restrict__ out)
{
    if (threadIdx.x == 0 && blockIdx.x == 0) {
        const float total = (float)c[0] + (float)c[1];
        out[0] = total / (float)(B * S * (NIN + NOUT) * T);
    }
}

// ---------------------------------------------------------------------------
extern "C" void kernel_launch(void* const* d_in, const int* in_sizes, int n_in,
                              void* d_out, int out_size, void* d_ws, size_t ws_size,
                              hipStream_t stream)
{
    const float* E    = (const float*)d_in[0];
    const float* Win  = (const float*)d_in[1];
    const float* bin  = (const float*)d_in[2];
    const float* Wc   = (const float*)d_in[3];
    const float* Wout = (const float*)d_in[4];
    const float* bout = (const float*)d_in[5];
    float* out = (float*)d_out;

    char* w = (char*)d_ws;
    float* snn              = (float*)(w);                          // 4 MB (later reused for WcT)
    unsigned short* WhT     = (unsigned short*)(w);                 // 2 MB (aliases snn, after lif_inA)
    unsigned short* WlT     = (unsigned short*)(w + (2 << 20));     // 2 MB
    unsigned long long* msk = (unsigned long long*)(w + (4 << 20)); // 4 MB
    float* sacc             = (float*)(w + (8 << 20));              // 4 MB
    unsigned int* sbits     = (unsigned int*)(w + (8 << 20));       // 4 MB (aliases sacc; dead before lif_out)
    float* vst              = (float*)(w + (12 << 20));             // 32 KB
    unsigned int* cnt       = (unsigned int*)(w + (12 << 20) + (64 << 10));
    float* Iout             = (float*)(w + (13 << 20));

    const size_t base = (size_t)13 << 20;
    const size_t avail = (ws_size > base) ? (ws_size - base) : 0;
    int P = 1;
    if      (avail >= (size_t)B * 128 * T * NOUT * 4) P = 128;
    else if (avail >= (size_t)B *  16 * T * NOUT * 4) P = 16;
    else if (avail >= (size_t)B *   4 * T * NOUT * 4) P = 4;

    k_init<<<1, 64, 0, stream>>>(cnt);

    dim3 g1(NIN / 64, (B * S) / 64);
    k_gemm<<<g1, 256, 0, stream>>>(E, Win, bin, snn, B * S, NIN, D, 1);

    k_lif_inA<<<128, 64, 0, stream>>>(snn, sbits, cnt);
    k_lif_inB<<<B * S, 256, 0, stream>>>(sbits, msk);

    // snn is dead now: build transposed hi/lo bf16 split of W_conn in its place
    dim3 gp(NIN / 64, NOUT / 64);
    k_prep<<<gp, 256, 0, stream>>>(Wc, WhT, WlT);

    for (int c = 0; c < S / P; ++c) {
        dim3 gc((B * P * T) / 256, NOUT / 64);
        k_conn_mfma<<<gc, 256, 0, stream>>>((const uint4*)msk, WhT, WlT, Iout, c * P, P);
        k_lif_out<<<128, 64, 0, stream>>>(Iout, vst, sacc, cnt, c * P, P, c == 0 ? 1 : 0);
    }

    dim3 g2(D / 64, (B * S) / 64);
    k_gemm<<<g2, 256, 0, stream>>>(sacc, Wout, bout, out, B * S, D, NOUT, 0);

    k_rate<<<1, 64, 0, stream>>>(cnt, out + (size_t)B * S * D);
}

// Round 18
// 435.439 us; speedup vs baseline: 1.0156x; 1.0156x over previous
//
#include <hip/hip_runtime.h>
#include <stdint.h>

#define B 8
#define S 128
#define D 512
#define NIN 1024
#define NOUT 1024
#define T 32

typedef __attribute__((ext_vector_type(8))) short short8;
typedef __attribute__((ext_vector_type(4))) float floatx4;

// direct global->LDS 16B copy (no VGPR round-trip, counted by vmcnt)
__device__ __forceinline__ void gload_lds16(const void* g, void* l)
{
    __builtin_amdgcn_global_load_lds(
        (const __attribute__((address_space(1))) unsigned int*)g,
        (__attribute__((address_space(3))) unsigned int*)l,
        16, 0, 0);
}

// ---------------------------------------------------------------------------
// Generic fp32 tiled GEMM: C[M,N] = maybe_relu(A[M,K] @ Bm[K,N] + bias[N])
// Register prefetch of the next k-slab before the FMA block (verified R2).
// ---------------------------------------------------------------------------
__global__ __launch_bounds__(256) void k_gemm(const float* __restrict__ A,
                                              const float* __restrict__ Bm,
                                              const float* __restrict__ bias,
                                              float* __restrict__ C,
                                              int M, int N, int K, int relu)
{
    __shared__ float As[16][64];
    __shared__ float Bs[16][64];
    const int tid = threadIdx.x;
    const int bx = blockIdx.x, by = blockIdx.y;
    const int tx = tid & 15, ty = tid >> 4;
    const int ar = tid >> 2, ak = (tid & 3) << 2;
    const int bk = tid >> 4, bc = (tid & 15) << 2;
    float acc[4][4] = {{0.f,0.f,0.f,0.f},{0.f,0.f,0.f,0.f},
                       {0.f,0.f,0.f,0.f},{0.f,0.f,0.f,0.f}};
    float4 a4 = *(const float4*)(A + (size_t)(by*64 + ar)*K + ak);
    float4 b4 = *(const float4*)(Bm + (size_t)bk*N + bx*64 + bc);
    for (int k0 = 0; k0 < K; k0 += 16) {
        __syncthreads();
        As[ak+0][ar] = a4.x; As[ak+1][ar] = a4.y;
        As[ak+2][ar] = a4.z; As[ak+3][ar] = a4.w;
        *(float4*)&Bs[bk][bc] = b4;
        float4 na, nb;
        const bool has = (k0 + 16 < K);
        if (has) {
            na = *(const float4*)(A + (size_t)(by*64 + ar)*K + k0 + 16 + ak);
            nb = *(const float4*)(Bm + (size_t)(k0 + 16 + bk)*N + bx*64 + bc);
        }
        __syncthreads();
        #pragma unroll
        for (int kk = 0; kk < 16; ++kk) {
            float4 av = *(const float4*)&As[kk][ty << 2];
            float4 bv = *(const float4*)&Bs[kk][tx << 2];
            acc[0][0] = fmaf(av.x, bv.x, acc[0][0]);
            acc[0][1] = fmaf(av.x, bv.y, acc[0][1]);
            acc[0][2] = fmaf(av.x, bv.z, acc[0][2]);
            acc[0][3] = fmaf(av.x, bv.w, acc[0][3]);
            acc[1][0] = fmaf(av.y, bv.x, acc[1][0]);
            acc[1][1] = fmaf(av.y, bv.y, acc[1][1]);
            acc[1][2] = fmaf(av.y, bv.z, acc[1][2]);
            acc[1][3] = fmaf(av.y, bv.w, acc[1][3]);
            acc[2][0] = fmaf(av.z, bv.x, acc[2][0]);
            acc[2][1] = fmaf(av.z, bv.y, acc[2][1]);
            acc[2][2] = fmaf(av.z, bv.z, acc[2][2]);
            acc[2][3] = fmaf(av.z, bv.w, acc[2][3]);
            acc[3][0] = fmaf(av.w, bv.x, acc[3][0]);
            acc[3][1] = fmaf(av.w, bv.y, acc[3][1]);
            acc[3][2] = fmaf(av.w, bv.z, acc[3][2]);
            acc[3][3] = fmaf(av.w, bv.w, acc[3][3]);
        }
        if (has) { a4 = na; b4 = nb; }
    }
    const int row0 = by*64 + (ty << 2), col0 = bx*64 + (tx << 2);
    float4 bb = *(const float4*)(bias + col0);
    #pragma unroll
    for (int i = 0; i < 4; ++i) {
        float4 o;
        o.x = acc[i][0] + bb.x; o.y = acc[i][1] + bb.y;
        o.z = acc[i][2] + bb.z; o.w = acc[i][3] + bb.w;
        if (relu) {
            o.x = fmaxf(o.x, 0.f); o.y = fmaxf(o.y, 0.f);
            o.z = fmaxf(o.z, 0.f); o.w = fmaxf(o.w, 0.f);
        }
        *(float4*)(C + (size_t)(row0 + i)*N + col0) = o;
    }
}

// ---------------------------------------------------------------------------
// Input LIF phase A — split form + depth-2 prefetch (R15/R17-measured).
// ---------------------------------------------------------------------------
__global__ __launch_bounds__(64) void k_lif_inA(const float* __restrict__ snn,
                                                unsigned int* __restrict__ sbits,
                                                unsigned int* __restrict__ counters)
{
    const int tid = blockIdx.x * 64 + threadIdx.x;   // 0..8191
    const int b = tid >> 10, n = tid & (NIN - 1);
    const float* cur = snn + (size_t)(b * S) * NIN + n;
    float v = 0.f;
    int cnt = 0;
    float I   = cur[0];
    float In1 = (1 < S) ? cur[(size_t)1 * NIN] : 0.f;
    for (int s = 0; s < S; ++s) {
        const float In2 = (s + 2 < S) ? cur[(size_t)(s + 2) * NIN] : 0.f;
        unsigned int bits = 0u;
        #pragma unroll
        for (int t = 0; t < T; ++t) {
            v = __fadd_rn(__fmul_rn(0.9f, v), I);
            const bool sp = (v >= 1.0f);
            v = sp ? (v - 1.0f) : v;
            bits |= (sp ? 1u : 0u) << t;
        }
        sbits[(size_t)(b * S + s) * NIN + n] = bits;
        cnt += __popc(bits);
        I = In1; In1 = In2;
    }
    atomicAdd(counters, (unsigned int)cnt);
}

// ---------------------------------------------------------------------------
// Input LIF phase B — R3-exact: parallel rebuild of the u64 ballot masks.
// ---------------------------------------------------------------------------
__global__ __launch_bounds__(256) void k_lif_inB(const unsigned int* __restrict__ sbits,
                                                 unsigned long long* __restrict__ masks)
{
    const int bs = blockIdx.x;                 // b*S+s
    const int w = threadIdx.x >> 6, lane = threadIdx.x & 63;
    #pragma unroll
    for (int i = 0; i < 4; ++i) {
        const int wq = w * 4 + i;
        const unsigned int bits = sbits[(size_t)bs * NIN + wq * 64 + lane];
        #pragma unroll
        for (int t = 0; t < T; ++t) {
            const unsigned long long m = __ballot((bits >> t) & 1u);
            if (lane == 0)
                masks[((size_t)bs * T + t) * 16 + wq] = m;
        }
    }
}

// ---------------------------------------------------------------------------
// Prep: transpose W_conn [k][n] -> WcT [n][k] and split fp32 = bf16_hi+bf16_lo
// ---------------------------------------------------------------------------
__global__ __launch_bounds__(256) void k_prep(const float* __restrict__ Wc,
                                              unsigned short* __restrict__ WhT,
                                              unsigned short* __restrict__ WlT)
{
    __shared__ float tile[64][65];
    const int k0 = blockIdx.x * 64, n0 = blockIdx.y * 64;
    const int tx = threadIdx.x & 63, ty = threadIdx.x >> 6;
    #pragma unroll
    for (int p = 0; p < 16; ++p) {
        const int kl = p*4 + ty;
        tile[kl][tx] = Wc[(size_t)(k0 + kl) * NOUT + n0 + tx];
    }
    __syncthreads();
    #pragma unroll
    for (int p = 0; p < 16; ++p) {
        const int nl = p*4 + ty;
        const float w = tile[tx][nl];
        const unsigned int u  = __float_as_uint(w);
        const unsigned int hb = (u + 0x7FFFu + ((u >> 16) & 1u)) & 0xFFFF0000u; // bf16 RNE
        const float hif = __uint_as_float(hb);
        const float lo  = w - hif;                                             // exact
        const unsigned int ul = __float_as_uint(lo);
        const unsigned short lob = (unsigned short)((ul + 0x7FFFu + ((ul >> 16) & 1u)) >> 16);
        WhT[(size_t)(n0 + nl) * NIN + k0 + tx] = (unsigned short)(hb >> 16);
        WlT[(size_t)(n0 + nl) * NIN + k0 + tx] = lob;
    }
}

// ---------------------------------------------------------------------------
// Spike GEMM via MFMA. R18: REVERT to the R15 LDS-LUT A-fragment (R17's VALU
// rebuild cost +12.5 us: 12 ops/frag on the MFMA-dependent path; LUT read =
// 1 instr + ~13 us conflict tax — net cheaper. Remaining 8.39e6 conflicts
// are structural staging-write cycles, exactly 2^23.)
// R18 probe: register double-buffer the B-fragments across kc — read kc+1's
// 8 ds_read_b128 BEFORE kc's 32-MFMA block so LDS traffic hides under the
// MFMA burst (the per-block barriers phase-align waves; this restores
// within-wave overlap). +32 VGPR (~212 total incl acc) -> occupancy
// unchanged. MFMA sequence (kc, f, c, hi->lo) identical -> Iout bit-identical.
// ---------------------------------------------------------------------------
__global__ __launch_bounds__(256) void k_conn_mfma(const uint4* __restrict__ masks128,
                                                   const unsigned short* __restrict__ WhT,
                                                   const unsigned short* __restrict__ WlT,
                                                   float* __restrict__ Iout,
                                                   int s0, int P)
{
    __shared__ uint4 lut[256];
    __shared__ unsigned short Bsm[2][2][64][128];   // [buf][mat][col][k] 64 KB

    const int tid = threadIdx.x;
    {
        const unsigned int bb = (unsigned int)tid;
        unsigned int r[4];
        #pragma unroll
        for (int i = 0; i < 4; ++i) {
            const unsigned int b0 = (bb >> (2*i)) & 1u, b1 = (bb >> (2*i+1)) & 1u;
            r[i] = (b0 ? 0x3F80u : 0u) | (b1 ? 0x3F800000u : 0u);
        }
        lut[tid] = make_uint4(r[0], r[1], r[2], r[3]);
    }

    const int w = tid >> 6, lane = tid & 63;
    const int r16 = lane & 15, q = lane >> 4;
    const int PT = P * T;
    const int rowblk = blockIdx.x * 256 + w * 64;
    const int cb = blockIdx.y * 64;

    const uint4* aptr[4];
    #pragma unroll
    for (int f = 0; f < 4; ++f) {
        const int r = rowblk + f*16 + r16;
        const int b = r / PT;
        const int within = r - b * PT;
        const int grow = (b * S + s0) * T + within;
        aptr[f] = masks128 + (size_t)grow * 8;
    }

    // per-thread staging sources (8 slots), with source-side XOR swizzle
    const unsigned short* stg_src[8];
    #pragma unroll
    for (int i = 0; i < 8; ++i) {
        const int flat = tid + i * 256;          // [mat(1)|col(6)|k16(4)]
        const int mat  = flat >> 10;
        const int col  = (flat >> 4) & 63;
        const int k16  = flat & 15;
        const int k16s = k16 ^ (col & 7);        // inverse swizzle on source
        stg_src[i] = (mat ? WlT : WhT) + (size_t)(cb + col) * NIN + k16s * 8;
    }

#define STAGE(BUF, CH) do {                                                   \
        char* dst0 = (char*)(&Bsm[BUF][0][0][0]) + (size_t)tid * 16;          \
        _Pragma("unroll")                                                     \
        for (int i_ = 0; i_ < 8; ++i_)                                        \
            gload_lds16(stg_src[i_] + (CH) * 128, dst0 + i_ * 4096);          \
    } while (0)

#define COMPUTE(BUF, AW) do {                                                 \
        short8 bh2[2][4], bl2[2][4];                                          \
        {                                                                     \
            const int kr0 = (q ^ (r16 & 7)) * 8;          /* kc=0 */          \
            _Pragma("unroll")                                                 \
            for (int c = 0; c < 4; ++c) {                                     \
                bh2[0][c] = *(const short8*)&Bsm[BUF][0][c*16 + r16][kr0];    \
                bl2[0][c] = *(const short8*)&Bsm[BUF][1][c*16 + r16][kr0];    \
            }                                                                 \
        }                                                                     \
        _Pragma("unroll")                                                     \
        for (int kc = 0; kc < 4; ++kc) {                                      \
            const int cur = kc & 1, nxt = cur ^ 1;                            \
            if (kc < 3) {                                                     \
                const int krn = (((kc+1)*4 + q) ^ (r16 & 7)) * 8;             \
                _Pragma("unroll")                                             \
                for (int c = 0; c < 4; ++c) {                                 \
                    bh2[nxt][c] = *(const short8*)&Bsm[BUF][0][c*16 + r16][krn]; \
                    bl2[nxt][c] = *(const short8*)&Bsm[BUF][1][c*16 + r16][krn]; \
                }                                                             \
            }                                                                 \
            _Pragma("unroll")                                                 \
            for (int f = 0; f < 4; ++f) {                                     \
                const unsigned int word = (kc == 0) ? AW[f].x                 \
                                        : (kc == 1) ? AW[f].y                 \
                                        : (kc == 2) ? AW[f].z : AW[f].w;      \
                const unsigned int byte = (word >> (q * 8)) & 0xFFu;          \
                const short8 a = *(const short8*)&lut[byte];                  \
                _Pragma("unroll")                                             \
                for (int c = 0; c < 4; ++c) {                                 \
                    acc[f][c] = __builtin_amdgcn_mfma_f32_16x16x32_bf16(      \
                                    a, bh2[cur][c], acc[f][c], 0, 0, 0);      \
                    acc[f][c] = __builtin_amdgcn_mfma_f32_16x16x32_bf16(      \
                                    a, bl2[cur][c], acc[f][c], 0, 0, 0);      \
                }                                                             \
            }                                                                 \
        }                                                                     \
    } while (0)

    floatx4 acc[4][4];
    #pragma unroll
    for (int f = 0; f < 4; ++f)
        #pragma unroll
        for (int c = 0; c < 4; ++c)
            acc[f][c] = (floatx4){0.f, 0.f, 0.f, 0.f};

    uint4 awA[4], awB[4];
    #pragma unroll
    for (int f = 0; f < 4; ++f) awA[f] = aptr[f][0];
    STAGE(0, 0);
    __syncthreads();            // drains stage(0) + LUT writes

    #pragma unroll 1
    for (int ch = 0; ch < 8; ch += 2) {
        // phase A: buf0 holds chunk ch; prefetch ch+1 into buf1
        STAGE(1, ch + 1);
        #pragma unroll
        for (int f = 0; f < 4; ++f) awB[f] = aptr[f][ch + 1];
        COMPUTE(0, awA);
        __syncthreads();        // stage(ch+1) done (hidden under MFMAs)

        // phase B: buf1 holds chunk ch+1; prefetch ch+2 into buf0
        if (ch + 2 < 8) {
            STAGE(0, ch + 2);
            #pragma unroll
            for (int f = 0; f < 4; ++f) awA[f] = aptr[f][ch + 2];
        }
        COMPUTE(1, awB);
        __syncthreads();
    }
#undef STAGE
#undef COMPUTE

    #pragma unroll
    for (int f = 0; f < 4; ++f) {
        const int row = rowblk + f*16 + q*4;
        #pragma unroll
        for (int c = 0; c < 4; ++c) {
            const int col = cb + c*16 + r16;
            #pragma unroll
            for (int i = 0; i < 4; ++i)
                Iout[(size_t)(row + i) * NOUT + col] = acc[f][c][i];
        }
    }
}

// ---------------------------------------------------------------------------
// Output-population LIF, 128x64 grid, depth-2 prefetch (R17, ~neutral).
// ---------------------------------------------------------------------------
__global__ __launch_bounds__(64) void k_lif_out(const float* __restrict__ Iout,
                                                float* __restrict__ vstate,
                                                float* __restrict__ sacc_out,
                                                unsigned int* __restrict__ counters,
                                                int s0, int P, int init)
{
    const int tid = blockIdx.x * 64 + threadIdx.x;
    const int b = tid >> 10, n = tid & (NOUT - 1);
    const int Tc = P * T;
    float v = init ? 0.f : vstate[tid];
    const float* ip = Iout + (size_t)b * Tc * NOUT + n;
    int cnt = 0;

    float cur[T], n1[T];
    #pragma unroll
    for (int t = 0; t < T; ++t) cur[t] = ip[(size_t)t * NOUT];
    if (1 < P) {
        const float* ip1 = ip + (size_t)T * NOUT;
        #pragma unroll
        for (int t = 0; t < T; ++t) n1[t] = ip1[(size_t)t * NOUT];
    }

    for (int sl = 0; sl < P; ++sl) {
        float n2[T];
        const bool has2 = (sl + 2 < P);
        if (has2) {
            const float* ip2 = ip + (size_t)(sl + 2) * T * NOUT;
            #pragma unroll
            for (int t = 0; t < T; ++t) n2[t] = ip2[(size_t)t * NOUT];
        }
        float sacc = 0.f;
        #pragma unroll
        for (int t = 0; t < T; ++t) {
            v = __fadd_rn(__fmul_rn(0.9f, v), cur[t]);
            const bool sp = (v >= 1.0f);
            v = sp ? (v - 1.0f) : v;
            sacc += sp ? 1.f : 0.f;
            cnt += sp ? 1 : 0;
        }
        sacc_out[(size_t)(b*S + s0 + sl) * NOUT + n] = sacc;
        if (sl + 1 < P) {
            #pragma unroll
            for (int t = 0; t < T; ++t) cur[t] = n1[t];
        }
        if (has2) {
            #pragma unroll
            for (int t = 0; t < T; ++t) n1[t] = n2[t];
        }
    }
    vstate[tid] = v;
    atomicAdd(counters + 1, (unsigned int)cnt);
}

__global__ void k_init(unsigned int* c)
{
    if (threadIdx.x < 2) c[threadIdx.x] = 0u;
}

__global__ void k_rate(const unsigned int* __restrict__ c, float* __restrict__ out)
{
    if (threadIdx.x == 0 && blockIdx.x == 0) {
        const float total = (float)c[0] + (float)c[1];
        out[0] = total / (float)(B * S * (NIN + NOUT) * T);
    }
}

// ---------------------------------------------------------------------------
extern "C" void kernel_launch(void* const* d_in, const int* in_sizes, int n_in,
                              void* d_out, int out_size, void* d_ws, size_t ws_size,
                              hipStream_t stream)
{
    const float* E    = (const float*)d_in[0];
    const float* Win  = (const float*)d_in[1];
    const float* bin  = (const float*)d_in[2];
    const float* Wc   = (const float*)d_in[3];
    const float* Wout = (const float*)d_in[4];
    const float* bout = (const float*)d_in[5];
    float* out = (float*)d_out;

    char* w = (char*)d_ws;
    float* snn              = (float*)(w);                          // 4 MB (later reused for WcT)
    unsigned short* WhT     = (unsigned short*)(w);                 // 2 MB (aliases snn, after lif_inA)
    unsigned short* WlT     = (unsigned short*)(w + (2 << 20));     // 2 MB
    unsigned long long* msk = (unsigned long long*)(w + (4 << 20)); // 4 MB
    float* sacc             = (float*)(w + (8 << 20));              // 4 MB
    unsigned int* sbits     = (unsigned int*)(w + (8 << 20));       // 4 MB (aliases sacc; dead before lif_out)
    float* vst              = (float*)(w + (12 << 20));             // 32 KB
    unsigned int* cnt       = (unsigned int*)(w + (12 << 20) + (64 << 10));
    float* Iout             = (float*)(w + (13 << 20));

    const size_t base = (size_t)13 << 20;
    const size_t avail = (ws_size > base) ? (ws_size - base) : 0;
    int P = 1;
    if      (avail >= (size_t)B * 128 * T * NOUT * 4) P = 128;
    else if (avail >= (size_t)B *  16 * T * NOUT * 4) P = 16;
    else if (avail >= (size_t)B *   4 * T * NOUT * 4) P = 4;

    k_init<<<1, 64, 0, stream>>>(cnt);

    dim3 g1(NIN / 64, (B * S) / 64);
    k_gemm<<<g1, 256, 0, stream>>>(E, Win, bin, snn, B * S, NIN, D, 1);

    k_lif_inA<<<128, 64, 0, stream>>>(snn, sbits, cnt);
    k_lif_inB<<<B * S, 256, 0, stream>>>(sbits, msk);

    // snn is dead now: build transposed hi/lo bf16 split of W_conn in its place
    dim3 gp(NIN / 64, NOUT / 64);
    k_prep<<<gp, 256, 0, stream>>>(Wc, WhT, WlT);

    for (int c = 0; c < S / P; ++c) {
        dim3 gc((B * P * T) / 256, NOUT / 64);
        k_conn_mfma<<<gc, 256, 0, stream>>>((const uint4*)msk, WhT, WlT, Iout, c * P, P);
        k_lif_out<<<128, 64, 0, stream>>>(Iout, vst, sacc, cnt, c * P, P, c == 0 ? 1 : 0);
    }

    dim3 g2(D / 64, (B * S) / 64);
    k_gemm<<<g2, 256, 0, stream>>>(sacc, Wout, bout, out, B * S, D, NOUT, 0);

    k_rate<<<1, 64, 0, stream>>>(cnt, out + (size_t)B * S * D);
}

// Round 19
// 434.922 us; speedup vs baseline: 1.0168x; 1.0012x over previous
//
#include <hip/hip_runtime.h>
#include <stdint.h>

#define B 8
#define S 128
#define D 512
#define NIN 1024
#define NOUT 1024
#define T 32

typedef __attribute__((ext_vector_type(8))) short short8;
typedef __attribute__((ext_vector_type(4))) float floatx4;

// direct global->LDS 16B copy (no VGPR round-trip, counted by vmcnt)
__device__ __forceinline__ void gload_lds16(const void* g, void* l)
{
    __builtin_amdgcn_global_load_lds(
        (const __attribute__((address_space(1))) unsigned int*)g,
        (__attribute__((address_space(3))) unsigned int*)l,
        16, 0, 0);
}

// ---------------------------------------------------------------------------
// Generic fp32 tiled GEMM: C[M,N] = maybe_relu(A[M,K] @ Bm[K,N] + bias[N])
// Register prefetch of the next k-slab before the FMA block (verified R2).
// ---------------------------------------------------------------------------
__global__ __launch_bounds__(256) void k_gemm(const float* __restrict__ A,
                                              const float* __restrict__ Bm,
                                              const float* __restrict__ bias,
                                              float* __restrict__ C,
                                              int M, int N, int K, int relu)
{
    __shared__ float As[16][64];
    __shared__ float Bs[16][64];
    const int tid = threadIdx.x;
    const int bx = blockIdx.x, by = blockIdx.y;
    const int tx = tid & 15, ty = tid >> 4;
    const int ar = tid >> 2, ak = (tid & 3) << 2;
    const int bk = tid >> 4, bc = (tid & 15) << 2;
    float acc[4][4] = {{0.f,0.f,0.f,0.f},{0.f,0.f,0.f,0.f},
                       {0.f,0.f,0.f,0.f},{0.f,0.f,0.f,0.f}};
    float4 a4 = *(const float4*)(A + (size_t)(by*64 + ar)*K + ak);
    float4 b4 = *(const float4*)(Bm + (size_t)bk*N + bx*64 + bc);
    for (int k0 = 0; k0 < K; k0 += 16) {
        __syncthreads();
        As[ak+0][ar] = a4.x; As[ak+1][ar] = a4.y;
        As[ak+2][ar] = a4.z; As[ak+3][ar] = a4.w;
        *(float4*)&Bs[bk][bc] = b4;
        float4 na, nb;
        const bool has = (k0 + 16 < K);
        if (has) {
            na = *(const float4*)(A + (size_t)(by*64 + ar)*K + k0 + 16 + ak);
            nb = *(const float4*)(Bm + (size_t)(k0 + 16 + bk)*N + bx*64 + bc);
        }
        __syncthreads();
        #pragma unroll
        for (int kk = 0; kk < 16; ++kk) {
            float4 av = *(const float4*)&As[kk][ty << 2];
            float4 bv = *(const float4*)&Bs[kk][tx << 2];
            acc[0][0] = fmaf(av.x, bv.x, acc[0][0]);
            acc[0][1] = fmaf(av.x, bv.y, acc[0][1]);
            acc[0][2] = fmaf(av.x, bv.z, acc[0][2]);
            acc[0][3] = fmaf(av.x, bv.w, acc[0][3]);
            acc[1][0] = fmaf(av.y, bv.x, acc[1][0]);
            acc[1][1] = fmaf(av.y, bv.y, acc[1][1]);
            acc[1][2] = fmaf(av.y, bv.z, acc[1][2]);
            acc[1][3] = fmaf(av.y, bv.w, acc[1][3]);
            acc[2][0] = fmaf(av.z, bv.x, acc[2][0]);
            acc[2][1] = fmaf(av.z, bv.y, acc[2][1]);
            acc[2][2] = fmaf(av.z, bv.z, acc[2][2]);
            acc[2][3] = fmaf(av.z, bv.w, acc[2][3]);
            acc[3][0] = fmaf(av.w, bv.x, acc[3][0]);
            acc[3][1] = fmaf(av.w, bv.y, acc[3][1]);
            acc[3][2] = fmaf(av.w, bv.z, acc[3][2]);
            acc[3][3] = fmaf(av.w, bv.w, acc[3][3]);
        }
        if (has) { a4 = na; b4 = nb; }
    }
    const int row0 = by*64 + (ty << 2), col0 = bx*64 + (tx << 2);
    float4 bb = *(const float4*)(bias + col0);
    #pragma unroll
    for (int i = 0; i < 4; ++i) {
        float4 o;
        o.x = acc[i][0] + bb.x; o.y = acc[i][1] + bb.y;
        o.z = acc[i][2] + bb.z; o.w = acc[i][3] + bb.w;
        if (relu) {
            o.x = fmaxf(o.x, 0.f); o.y = fmaxf(o.y, 0.f);
            o.z = fmaxf(o.z, 0.f); o.w = fmaxf(o.w, 0.f);
        }
        *(float4*)(C + (size_t)(row0 + i)*N + col0) = o;
    }
}

// ---------------------------------------------------------------------------
// Input LIF phase A — split form + depth-2 prefetch (R15/R17-measured).
// ---------------------------------------------------------------------------
__global__ __launch_bounds__(64) void k_lif_inA(const float* __restrict__ snn,
                                                unsigned int* __restrict__ sbits,
                                                unsigned int* __restrict__ counters)
{
    const int tid = blockIdx.x * 64 + threadIdx.x;   // 0..8191
    const int b = tid >> 10, n = tid & (NIN - 1);
    const float* cur = snn + (size_t)(b * S) * NIN + n;
    float v = 0.f;
    int cnt = 0;
    float I   = cur[0];
    float In1 = (1 < S) ? cur[(size_t)1 * NIN] : 0.f;
    for (int s = 0; s < S; ++s) {
        const float In2 = (s + 2 < S) ? cur[(size_t)(s + 2) * NIN] : 0.f;
        unsigned int bits = 0u;
        #pragma unroll
        for (int t = 0; t < T; ++t) {
            v = __fadd_rn(__fmul_rn(0.9f, v), I);
            const bool sp = (v >= 1.0f);
            v = sp ? (v - 1.0f) : v;
            bits |= (sp ? 1u : 0u) << t;
        }
        sbits[(size_t)(b * S + s) * NIN + n] = bits;
        cnt += __popc(bits);
        I = In1; In1 = In2;
    }
    atomicAdd(counters, (unsigned int)cnt);
}

// ---------------------------------------------------------------------------
// Input LIF phase B — R3-exact: parallel rebuild of the u64 ballot masks.
// ---------------------------------------------------------------------------
__global__ __launch_bounds__(256) void k_lif_inB(const unsigned int* __restrict__ sbits,
                                                 unsigned long long* __restrict__ masks)
{
    const int bs = blockIdx.x;                 // b*S+s
    const int w = threadIdx.x >> 6, lane = threadIdx.x & 63;
    #pragma unroll
    for (int i = 0; i < 4; ++i) {
        const int wq = w * 4 + i;
        const unsigned int bits = sbits[(size_t)bs * NIN + wq * 64 + lane];
        #pragma unroll
        for (int t = 0; t < T; ++t) {
            const unsigned long long m = __ballot((bits >> t) & 1u);
            if (lane == 0)
                masks[((size_t)bs * T + t) * 16 + wq] = m;
        }
    }
}

// ---------------------------------------------------------------------------
// Prep: transpose W_conn [k][n] -> WcT [n][k] and split fp32 = bf16_hi+bf16_lo
// ---------------------------------------------------------------------------
__global__ __launch_bounds__(256) void k_prep(const float* __restrict__ Wc,
                                              unsigned short* __restrict__ WhT,
                                              unsigned short* __restrict__ WlT)
{
    __shared__ float tile[64][65];
    const int k0 = blockIdx.x * 64, n0 = blockIdx.y * 64;
    const int tx = threadIdx.x & 63, ty = threadIdx.x >> 6;
    #pragma unroll
    for (int p = 0; p < 16; ++p) {
        const int kl = p*4 + ty;
        tile[kl][tx] = Wc[(size_t)(k0 + kl) * NOUT + n0 + tx];
    }
    __syncthreads();
    #pragma unroll
    for (int p = 0; p < 16; ++p) {
        const int nl = p*4 + ty;
        const float w = tile[tx][nl];
        const unsigned int u  = __float_as_uint(w);
        const unsigned int hb = (u + 0x7FFFu + ((u >> 16) & 1u)) & 0xFFFF0000u; // bf16 RNE
        const float hif = __uint_as_float(hb);
        const float lo  = w - hif;                                             // exact
        const unsigned int ul = __float_as_uint(lo);
        const unsigned short lob = (unsigned short)((ul + 0x7FFFu + ((ul >> 16) & 1u)) >> 16);
        WhT[(size_t)(n0 + nl) * NIN + k0 + tx] = (unsigned short)(hb >> 16);
        WlT[(size_t)(n0 + nl) * NIN + k0 + tx] = lob;
    }
}

// ---------------------------------------------------------------------------
// Spike GEMM via MFMA — R15-exact structure (119.7 us measured) restored
// (R18's kc-double-buffer was compiler-folded: VGPR identical, +2.8 us).
// R19 probe: XCD-aware block remap. FETCH_SIZE=25 MB vs 8 MB true working
// set => W panels re-fetched ~5x across the 8 per-XCD L2s. Remap so each
// XCD owns 2 complete by-panels (bid=bx+by*128; k=bid&7; j=bid>>3;
// by=2k+(j>>7); bx=j&127 — bijective), making gload_lds staging L2-local.
// MFMA sequence unchanged -> Iout bit-identical.
// ---------------------------------------------------------------------------
__global__ __launch_bounds__(256) void k_conn_mfma(const uint4* __restrict__ masks128,
                                                   const unsigned short* __restrict__ WhT,
                                                   const unsigned short* __restrict__ WlT,
                                                   float* __restrict__ Iout,
                                                   int s0, int P)
{
    __shared__ uint4 lut[256];
    __shared__ unsigned short Bsm[2][2][64][128];   // [buf][mat][col][k] 64 KB

    const int tid = threadIdx.x;
    {
        const unsigned int bb = (unsigned int)tid;
        unsigned int r[4];
        #pragma unroll
        for (int i = 0; i < 4; ++i) {
            const unsigned int b0 = (bb >> (2*i)) & 1u, b1 = (bb >> (2*i+1)) & 1u;
            r[i] = (b0 ? 0x3F80u : 0u) | (b1 ? 0x3F800000u : 0u);
        }
        lut[tid] = make_uint4(r[0], r[1], r[2], r[3]);
    }

    // XCD-aware remap: keep all blocks of a cb-panel on one XCD's L2
    const int bid = blockIdx.x + blockIdx.y * gridDim.x;   // hw linear id
    const int xcd = bid & 7;
    const int j   = bid >> 3;
    const int bxe = j & 127;                               // 0..127
    const int bye = 2 * xcd + (j >> 7);                    // 0..15

    const int w = tid >> 6, lane = tid & 63;
    const int r16 = lane & 15, q = lane >> 4;
    const int PT = P * T;
    const int rowblk = bxe * 256 + w * 64;
    const int cb = bye * 64;

    const uint4* aptr[4];
    #pragma unroll
    for (int f = 0; f < 4; ++f) {
        const int r = rowblk + f*16 + r16;
        const int b = r / PT;
        const int within = r - b * PT;
        const int grow = (b * S + s0) * T + within;
        aptr[f] = masks128 + (size_t)grow * 8;
    }

    // per-thread staging sources (8 slots), with source-side XOR swizzle
    const unsigned short* stg_src[8];
    #pragma unroll
    for (int i = 0; i < 8; ++i) {
        const int flat = tid + i * 256;          // [mat(1)|col(6)|k16(4)]
        const int mat  = flat >> 10;
        const int col  = (flat >> 4) & 63;
        const int k16  = flat & 15;
        const int k16s = k16 ^ (col & 7);        // inverse swizzle on source
        stg_src[i] = (mat ? WlT : WhT) + (size_t)(cb + col) * NIN + k16s * 8;
    }

#define STAGE(BUF, CH) do {                                                   \
        char* dst0 = (char*)(&Bsm[BUF][0][0][0]) + (size_t)tid * 16;          \
        _Pragma("unroll")                                                     \
        for (int i_ = 0; i_ < 8; ++i_)                                        \
            gload_lds16(stg_src[i_] + (CH) * 128, dst0 + i_ * 4096);          \
    } while (0)

#define COMPUTE(BUF, AW) do {                                                 \
        _Pragma("unroll")                                                     \
        for (int kc = 0; kc < 4; ++kc) {                                      \
            short8 bh[4], bl[4];                                              \
            const int kread = ((kc*4 + q) ^ (r16 & 7)) * 8;                   \
            _Pragma("unroll")                                                 \
            for (int c = 0; c < 4; ++c) {                                     \
                bh[c] = *(const short8*)&Bsm[BUF][0][c*16 + r16][kread];      \
                bl[c] = *(const short8*)&Bsm[BUF][1][c*16 + r16][kread];      \
            }                                                                 \
            _Pragma("unroll")                                                 \
            for (int f = 0; f < 4; ++f) {                                     \
                const unsigned int word = (kc == 0) ? AW[f].x                 \
                                        : (kc == 1) ? AW[f].y                 \
                                        : (kc == 2) ? AW[f].z : AW[f].w;      \
                const unsigned int byte = (word >> (q * 8)) & 0xFFu;          \
                const short8 a = *(const short8*)&lut[byte];                  \
                _Pragma("unroll")                                             \
                for (int c = 0; c < 4; ++c) {                                 \
                    acc[f][c] = __builtin_amdgcn_mfma_f32_16x16x32_bf16(      \
                                    a, bh[c], acc[f][c], 0, 0, 0);            \
                    acc[f][c] = __builtin_amdgcn_mfma_f32_16x16x32_bf16(      \
                                    a, bl[c], acc[f][c], 0, 0, 0);            \
                }                                                             \
            }                                                                 \
        }                                                                     \
    } while (0)

    floatx4 acc[4][4];
    #pragma unroll
    for (int f = 0; f < 4; ++f)
        #pragma unroll
        for (int c = 0; c < 4; ++c)
            acc[f][c] = (floatx4){0.f, 0.f, 0.f, 0.f};

    uint4 awA[4], awB[4];
    #pragma unroll
    for (int f = 0; f < 4; ++f) awA[f] = aptr[f][0];
    STAGE(0, 0);
    __syncthreads();            // drains stage(0) + LUT writes

    #pragma unroll 1
    for (int ch = 0; ch < 8; ch += 2) {
        // phase A: buf0 holds chunk ch; prefetch ch+1 into buf1
        STAGE(1, ch + 1);
        #pragma unroll
        for (int f = 0; f < 4; ++f) awB[f] = aptr[f][ch + 1];
        COMPUTE(0, awA);
        __syncthreads();        // stage(ch+1) done (hidden under MFMAs)

        // phase B: buf1 holds chunk ch+1; prefetch ch+2 into buf0
        if (ch + 2 < 8) {
            STAGE(0, ch + 2);
            #pragma unroll
            for (int f = 0; f < 4; ++f) awA[f] = aptr[f][ch + 2];
        }
        COMPUTE(1, awB);
        __syncthreads();
    }
#undef STAGE
#undef COMPUTE

    #pragma unroll
    for (int f = 0; f < 4; ++f) {
        const int row = rowblk + f*16 + q*4;
        #pragma unroll
        for (int c = 0; c < 4; ++c) {
            const int col = cb + c*16 + r16;
            #pragma unroll
            for (int i = 0; i < 4; ++i)
                Iout[(size_t)(row + i) * NOUT + col] = acc[f][c][i];
        }
    }
}

// ---------------------------------------------------------------------------
// Output-population LIF, 128x64 grid, depth-2 prefetch (R17/R18, neutral).
// ---------------------------------------------------------------------------
__global__ __launch_bounds__(64) void k_lif_out(const float* __restrict__ Iout,
                                                float* __restrict__ vstate,
                                                float* __restrict__ sacc_out,
                                                unsigned int* __restrict__ counters,
                                                int s0, int P, int init)
{
    const int tid = blockIdx.x * 64 + threadIdx.x;
    const int b = tid >> 10, n = tid & (NOUT - 1);
    const int Tc = P * T;
    float v = init ? 0.f : vstate[tid];
    const float* ip = Iout + (size_t)b * Tc * NOUT + n;
    int cnt = 0;

    float cur[T], n1[T];
    #pragma unroll
    for (int t = 0; t < T; ++t) cur[t] = ip[(size_t)t * NOUT];
    if (1 < P) {
        const float* ip1 = ip + (size_t)T * NOUT;
        #pragma unroll
        for (int t = 0; t < T; ++t) n1[t] = ip1[(size_t)t * NOUT];
    }

    for (int sl = 0; sl < P; ++sl) {
        float n2[T];
        const bool has2 = (sl + 2 < P);
        if (has2) {
            const float* ip2 = ip + (size_t)(sl + 2) * T * NOUT;
            #pragma unroll
            for (int t = 0; t < T; ++t) n2[t] = ip2[(size_t)t * NOUT];
        }
        float sacc = 0.f;
        #pragma unroll
        for (int t = 0; t < T; ++t) {
            v = __fadd_rn(__fmul_rn(0.9f, v), cur[t]);
            const bool sp = (v >= 1.0f);
            v = sp ? (v - 1.0f) : v;
            sacc += sp ? 1.f : 0.f;
            cnt += sp ? 1 : 0;
        }
        sacc_out[(size_t)(b*S + s0 + sl) * NOUT + n] = sacc;
        if (sl + 1 < P) {
            #pragma unroll
            for (int t = 0; t < T; ++t) cur[t] = n1[t];
        }
        if (has2) {
            #pragma unroll
            for (int t = 0; t < T; ++t) n1[t] = n2[t];
        }
    }
    vstate[tid] = v;
    atomicAdd(counters + 1, (unsigned int)cnt);
}

__global__ void k_init(unsigned int* c)
{
    if (threadIdx.x < 2) c[threadIdx.x] = 0u;
}

__global__ void k_rate(const unsigned int* __restrict__ c, float* __restrict__ out)
{
    if (threadIdx.x == 0 && blockIdx.x == 0) {
        const float total = (float)c[0] + (float)c[1];
        out[0] = total / (float)(B * S * (NIN + NOUT) * T);
    }
}

// ---------------------------------------------------------------------------
extern "C" void kernel_launch(void* const* d_in, const int* in_sizes, int n_in,
                              void* d_out, int out_size, void* d_ws, size_t ws_size,
                              hipStream_t stream)
{
    const float* E    = (const float*)d_in[0];
    const float* Win  = (const float*)d_in[1];
    const float* bin  = (const float*)d_in[2];
    const float* Wc   = (const float*)d_in[3];
    const float* Wout = (const float*)d_in[4];
    const float* bout = (const float*)d_in[5];
    float* out = (float*)d_out;

    char* w = (char*)d_ws;
    float* snn              = (float*)(w);                          // 4 MB (later reused for WcT)
    unsigned short* WhT     = (unsigned short*)(w);                 // 2 MB (aliases snn, after lif_inA)
    unsigned short* WlT     = (unsigned short*)(w + (2 << 20));     // 2 MB
    unsigned long long* msk = (unsigned long long*)(w + (4 << 20)); // 4 MB
    float* sacc             = (float*)(w + (8 << 20));              // 4 MB
    unsigned int* sbits     = (unsigned int*)(w + (8 << 20));       // 4 MB (aliases sacc; dead before lif_out)
    float* vst              = (float*)(w + (12 << 20));             // 32 KB
    unsigned int* cnt       = (unsigned int*)(w + (12 << 20) + (64 << 10));
    float* Iout             = (float*)(w + (13 << 20));

    const size_t base = (size_t)13 << 20;
    const size_t avail = (ws_size > base) ? (ws_size - base) : 0;
    int P = 1;
    if      (avail >= (size_t)B * 128 * T * NOUT * 4) P = 128;
    else if (avail >= (size_t)B *  16 * T * NOUT * 4) P = 16;
    else if (avail >= (size_t)B *   4 * T * NOUT * 4) P = 4;

    k_init<<<1, 64, 0, stream>>>(cnt);

    dim3 g1(NIN / 64, (B * S) / 64);
    k_gemm<<<g1, 256, 0, stream>>>(E, Win, bin, snn, B * S, NIN, D, 1);

    k_lif_inA<<<128, 64, 0, stream>>>(snn, sbits, cnt);
    k_lif_inB<<<B * S, 256, 0, stream>>>(sbits, msk);

    // snn is dead now: build transposed hi/lo bf16 split of W_conn in its place
    dim3 gp(NIN / 64, NOUT / 64);
    k_prep<<<gp, 256, 0, stream>>>(Wc, WhT, WlT);

    for (int c = 0; c < S / P; ++c) {
        dim3 gc((B * P * T) / 256, NOUT / 64);
        k_conn_mfma<<<gc, 256, 0, stream>>>((const uint4*)msk, WhT, WlT, Iout, c * P, P);
        k_lif_out<<<128, 64, 0, stream>>>(Iout, vst, sacc, cnt, c * P, P, c == 0 ? 1 : 0);
    }

    dim3 g2(D / 64, (B * S) / 64);
    k_gemm<<<g2, 256, 0, stream>>>(sacc, Wout, bout, out, B * S, D, NOUT, 0);

    k_rate<<<1, 64, 0, stream>>>(cnt, out + (size_t)B * S * D);
}

// Round 20
// 427.584 us; speedup vs baseline: 1.0342x; 1.0172x over previous
//
#include <hip/hip_runtime.h>
#include <stdint.h>

#define B 8
#define S 128
#define D 512
#define NIN 1024
#define NOUT 1024
#define T 32

typedef __attribute__((ext_vector_type(8))) short short8;
typedef __attribute__((ext_vector_type(4))) float floatx4;

// direct global->LDS 16B copy (no VGPR round-trip, counted by vmcnt)
__device__ __forceinline__ void gload_lds16(const void* g, void* l)
{
    __builtin_amdgcn_global_load_lds(
        (const __attribute__((address_space(1))) unsigned int*)g,
        (__attribute__((address_space(3))) unsigned int*)l,
        16, 0, 0);
}

// ---------------------------------------------------------------------------
// Generic fp32 tiled GEMM: C[M,N] = maybe_relu(A[M,K] @ Bm[K,N] + bias[N])
// Register prefetch of the next k-slab before the FMA block (verified R2).
// ---------------------------------------------------------------------------
__global__ __launch_bounds__(256) void k_gemm(const float* __restrict__ A,
                                              const float* __restrict__ Bm,
                                              const float* __restrict__ bias,
                                              float* __restrict__ C,
                                              int M, int N, int K, int relu)
{
    __shared__ float As[16][64];
    __shared__ float Bs[16][64];
    const int tid = threadIdx.x;
    const int bx = blockIdx.x, by = blockIdx.y;
    const int tx = tid & 15, ty = tid >> 4;
    const int ar = tid >> 2, ak = (tid & 3) << 2;
    const int bk = tid >> 4, bc = (tid & 15) << 2;
    float acc[4][4] = {{0.f,0.f,0.f,0.f},{0.f,0.f,0.f,0.f},
                       {0.f,0.f,0.f,0.f},{0.f,0.f,0.f,0.f}};
    float4 a4 = *(const float4*)(A + (size_t)(by*64 + ar)*K + ak);
    float4 b4 = *(const float4*)(Bm + (size_t)bk*N + bx*64 + bc);
    for (int k0 = 0; k0 < K; k0 += 16) {
        __syncthreads();
        As[ak+0][ar] = a4.x; As[ak+1][ar] = a4.y;
        As[ak+2][ar] = a4.z; As[ak+3][ar] = a4.w;
        *(float4*)&Bs[bk][bc] = b4;
        float4 na, nb;
        const bool has = (k0 + 16 < K);
        if (has) {
            na = *(const float4*)(A + (size_t)(by*64 + ar)*K + k0 + 16 + ak);
            nb = *(const float4*)(Bm + (size_t)(k0 + 16 + bk)*N + bx*64 + bc);
        }
        __syncthreads();
        #pragma unroll
        for (int kk = 0; kk < 16; ++kk) {
            float4 av = *(const float4*)&As[kk][ty << 2];
            float4 bv = *(const float4*)&Bs[kk][tx << 2];
            acc[0][0] = fmaf(av.x, bv.x, acc[0][0]);
            acc[0][1] = fmaf(av.x, bv.y, acc[0][1]);
            acc[0][2] = fmaf(av.x, bv.z, acc[0][2]);
            acc[0][3] = fmaf(av.x, bv.w, acc[0][3]);
            acc[1][0] = fmaf(av.y, bv.x, acc[1][0]);
            acc[1][1] = fmaf(av.y, bv.y, acc[1][1]);
            acc[1][2] = fmaf(av.y, bv.z, acc[1][2]);
            acc[1][3] = fmaf(av.y, bv.w, acc[1][3]);
            acc[2][0] = fmaf(av.z, bv.x, acc[2][0]);
            acc[2][1] = fmaf(av.z, bv.y, acc[2][1]);
            acc[2][2] = fmaf(av.z, bv.z, acc[2][2]);
            acc[2][3] = fmaf(av.z, bv.w, acc[2][3]);
            acc[3][0] = fmaf(av.w, bv.x, acc[3][0]);
            acc[3][1] = fmaf(av.w, bv.y, acc[3][1]);
            acc[3][2] = fmaf(av.w, bv.z, acc[3][2]);
            acc[3][3] = fmaf(av.w, bv.w, acc[3][3]);
        }
        if (has) { a4 = na; b4 = nb; }
    }
    const int row0 = by*64 + (ty << 2), col0 = bx*64 + (tx << 2);
    float4 bb = *(const float4*)(bias + col0);
    #pragma unroll
    for (int i = 0; i < 4; ++i) {
        float4 o;
        o.x = acc[i][0] + bb.x; o.y = acc[i][1] + bb.y;
        o.z = acc[i][2] + bb.z; o.w = acc[i][3] + bb.w;
        if (relu) {
            o.x = fmaxf(o.x, 0.f); o.y = fmaxf(o.y, 0.f);
            o.z = fmaxf(o.z, 0.f); o.w = fmaxf(o.w, 0.f);
        }
        *(float4*)(C + (size_t)(row0 + i)*N + col0) = o;
    }
}

// ---------------------------------------------------------------------------
// Input LIF phase A — split form + depth-2 prefetch (R15-measured, 428.5 us
// config). One chain/thread, 8192 threads over 128 CUs.
// ---------------------------------------------------------------------------
__global__ __launch_bounds__(64) void k_lif_inA(const float* __restrict__ snn,
                                                unsigned int* __restrict__ sbits,
                                                unsigned int* __restrict__ counters)
{
    const int tid = blockIdx.x * 64 + threadIdx.x;   // 0..8191
    const int b = tid >> 10, n = tid & (NIN - 1);
    const float* cur = snn + (size_t)(b * S) * NIN + n;
    float v = 0.f;
    int cnt = 0;
    float I   = cur[0];
    float In1 = (1 < S) ? cur[(size_t)1 * NIN] : 0.f;
    for (int s = 0; s < S; ++s) {
        const float In2 = (s + 2 < S) ? cur[(size_t)(s + 2) * NIN] : 0.f;
        unsigned int bits = 0u;
        #pragma unroll
        for (int t = 0; t < T; ++t) {
            v = __fadd_rn(__fmul_rn(0.9f, v), I);
            const bool sp = (v >= 1.0f);
            v = sp ? (v - 1.0f) : v;
            bits |= (sp ? 1u : 0u) << t;
        }
        sbits[(size_t)(b * S + s) * NIN + n] = bits;
        cnt += __popc(bits);
        I = In1; In1 = In2;
    }
    atomicAdd(counters, (unsigned int)cnt);
}

// ---------------------------------------------------------------------------
// Input LIF phase B — R3-exact: parallel rebuild of the u64 ballot masks.
// ---------------------------------------------------------------------------
__global__ __launch_bounds__(256) void k_lif_inB(const unsigned int* __restrict__ sbits,
                                                 unsigned long long* __restrict__ masks)
{
    const int bs = blockIdx.x;                 // b*S+s
    const int w = threadIdx.x >> 6, lane = threadIdx.x & 63;
    #pragma unroll
    for (int i = 0; i < 4; ++i) {
        const int wq = w * 4 + i;
        const unsigned int bits = sbits[(size_t)bs * NIN + wq * 64 + lane];
        #pragma unroll
        for (int t = 0; t < T; ++t) {
            const unsigned long long m = __ballot((bits >> t) & 1u);
            if (lane == 0)
                masks[((size_t)bs * T + t) * 16 + wq] = m;
        }
    }
}

// ---------------------------------------------------------------------------
// Prep: transpose W_conn [k][n] -> WcT [n][k] and split fp32 = bf16_hi+bf16_lo
// ---------------------------------------------------------------------------
__global__ __launch_bounds__(256) void k_prep(const float* __restrict__ Wc,
                                              unsigned short* __restrict__ WhT,
                                              unsigned short* __restrict__ WlT)
{
    __shared__ float tile[64][65];
    const int k0 = blockIdx.x * 64, n0 = blockIdx.y * 64;
    const int tx = threadIdx.x & 63, ty = threadIdx.x >> 6;
    #pragma unroll
    for (int p = 0; p < 16; ++p) {
        const int kl = p*4 + ty;
        tile[kl][tx] = Wc[(size_t)(k0 + kl) * NOUT + n0 + tx];
    }
    __syncthreads();
    #pragma unroll
    for (int p = 0; p < 16; ++p) {
        const int nl = p*4 + ty;
        const float w = tile[tx][nl];
        const unsigned int u  = __float_as_uint(w);
        const unsigned int hb = (u + 0x7FFFu + ((u >> 16) & 1u)) & 0xFFFF0000u; // bf16 RNE
        const float hif = __uint_as_float(hb);
        const float lo  = w - hif;                                             // exact
        const unsigned int ul = __float_as_uint(lo);
        const unsigned short lob = (unsigned short)((ul + 0x7FFFu + ((ul >> 16) & 1u)) >> 16);
        WhT[(size_t)(n0 + nl) * NIN + k0 + tx] = (unsigned short)(hb >> 16);
        WlT[(size_t)(n0 + nl) * NIN + k0 + tx] = lob;
    }
}

// ---------------------------------------------------------------------------
// Spike GEMM via MFMA — R15-exact (119.7 us measured; session best).
// Plateau documented across R3-R19: BK=64 (+12%), f=8 (+14%, VGPR cliff),
// launch-bounds cap (spill disaster), VALU A-frag (+12.5 us), kc-dbuf
// (compiler-folded, +2.8), XCD remap (FETCH 2x, dur flat -> staging fully
// hidden). Structure: MFMA 66 us floor + co-critical LDS at 2 blocks/CU;
// compiler already saturates within-wave ds_read->MFMA scheduling.
// ---------------------------------------------------------------------------
__global__ __launch_bounds__(256) void k_conn_mfma(const uint4* __restrict__ masks128,
                                                   const unsigned short* __restrict__ WhT,
                                                   const unsigned short* __restrict__ WlT,
                                                   float* __restrict__ Iout,
                                                   int s0, int P)
{
    __shared__ uint4 lut[256];
    __shared__ unsigned short Bsm[2][2][64][128];   // [buf][mat][col][k] 64 KB

    const int tid = threadIdx.x;
    {
        const unsigned int bb = (unsigned int)tid;
        unsigned int r[4];
        #pragma unroll
        for (int i = 0; i < 4; ++i) {
            const unsigned int b0 = (bb >> (2*i)) & 1u, b1 = (bb >> (2*i+1)) & 1u;
            r[i] = (b0 ? 0x3F80u : 0u) | (b1 ? 0x3F800000u : 0u);
        }
        lut[tid] = make_uint4(r[0], r[1], r[2], r[3]);
    }

    const int w = tid >> 6, lane = tid & 63;
    const int r16 = lane & 15, q = lane >> 4;
    const int PT = P * T;
    const int rowblk = blockIdx.x * 256 + w * 64;
    const int cb = blockIdx.y * 64;

    const uint4* aptr[4];
    #pragma unroll
    for (int f = 0; f < 4; ++f) {
        const int r = rowblk + f*16 + r16;
        const int b = r / PT;
        const int within = r - b * PT;
        const int grow = (b * S + s0) * T + within;
        aptr[f] = masks128 + (size_t)grow * 8;
    }

    // per-thread staging sources (8 slots), with source-side XOR swizzle
    const unsigned short* stg_src[8];
    #pragma unroll
    for (int i = 0; i < 8; ++i) {
        const int flat = tid + i * 256;          // [mat(1)|col(6)|k16(4)]
        const int mat  = flat >> 10;
        const int col  = (flat >> 4) & 63;
        const int k16  = flat & 15;
        const int k16s = k16 ^ (col & 7);        // inverse swizzle on source
        stg_src[i] = (mat ? WlT : WhT) + (size_t)(cb + col) * NIN + k16s * 8;
    }

#define STAGE(BUF, CH) do {                                                   \
        char* dst0 = (char*)(&Bsm[BUF][0][0][0]) + (size_t)tid * 16;          \
        _Pragma("unroll")                                                     \
        for (int i_ = 0; i_ < 8; ++i_)                                        \
            gload_lds16(stg_src[i_] + (CH) * 128, dst0 + i_ * 4096);          \
    } while (0)

#define COMPUTE(BUF, AW) do {                                                 \
        _Pragma("unroll")                                                     \
        for (int kc = 0; kc < 4; ++kc) {                                      \
            short8 bh[4], bl[4];                                              \
            const int kread = ((kc*4 + q) ^ (r16 & 7)) * 8;                   \
            _Pragma("unroll")                                                 \
            for (int c = 0; c < 4; ++c) {                                     \
                bh[c] = *(const short8*)&Bsm[BUF][0][c*16 + r16][kread];      \
                bl[c] = *(const short8*)&Bsm[BUF][1][c*16 + r16][kread];      \
            }                                                                 \
            _Pragma("unroll")                                                 \
            for (int f = 0; f < 4; ++f) {                                     \
                const unsigned int word = (kc == 0) ? AW[f].x                 \
                                        : (kc == 1) ? AW[f].y                 \
                                        : (kc == 2) ? AW[f].z : AW[f].w;      \
                const unsigned int byte = (word >> (q * 8)) & 0xFFu;          \
                const short8 a = *(const short8*)&lut[byte];                  \
                _Pragma("unroll")                                             \
                for (int c = 0; c < 4; ++c) {                                 \
                    acc[f][c] = __builtin_amdgcn_mfma_f32_16x16x32_bf16(      \
                                    a, bh[c], acc[f][c], 0, 0, 0);            \
                    acc[f][c] = __builtin_amdgcn_mfma_f32_16x16x32_bf16(      \
                                    a, bl[c], acc[f][c], 0, 0, 0);            \
                }                                                             \
            }                                                                 \
        }                                                                     \
    } while (0)

    floatx4 acc[4][4];
    #pragma unroll
    for (int f = 0; f < 4; ++f)
        #pragma unroll
        for (int c = 0; c < 4; ++c)
            acc[f][c] = (floatx4){0.f, 0.f, 0.f, 0.f};

    uint4 awA[4], awB[4];
    #pragma unroll
    for (int f = 0; f < 4; ++f) awA[f] = aptr[f][0];
    STAGE(0, 0);
    __syncthreads();            // drains stage(0) + LUT writes

    #pragma unroll 1
    for (int ch = 0; ch < 8; ch += 2) {
        // phase A: buf0 holds chunk ch; prefetch ch+1 into buf1
        STAGE(1, ch + 1);
        #pragma unroll
        for (int f = 0; f < 4; ++f) awB[f] = aptr[f][ch + 1];
        COMPUTE(0, awA);
        __syncthreads();        // stage(ch+1) done (hidden under MFMAs)

        // phase B: buf1 holds chunk ch+1; prefetch ch+2 into buf0
        if (ch + 2 < 8) {
            STAGE(0, ch + 2);
            #pragma unroll
            for (int f = 0; f < 4; ++f) awA[f] = aptr[f][ch + 2];
        }
        COMPUTE(1, awB);
        __syncthreads();
    }
#undef STAGE
#undef COMPUTE

    #pragma unroll
    for (int f = 0; f < 4; ++f) {
        const int row = rowblk + f*16 + q*4;
        #pragma unroll
        for (int c = 0; c < 4; ++c) {
            const int col = cb + c*16 + r16;
            #pragma unroll
            for (int i = 0; i < 4; ++i)
                Iout[(size_t)(row + i) * NOUT + col] = acc[f][c][i];
        }
    }
}

// ---------------------------------------------------------------------------
// Output-population LIF, 128x64 grid, depth-1 prefetch (R15-measured best;
// R17's depth-2 variant measured ~+4 us worse in the R18/R19 accounting).
// ---------------------------------------------------------------------------
__global__ __launch_bounds__(64) void k_lif_out(const float* __restrict__ Iout,
                                                float* __restrict__ vstate,
                                                float* __restrict__ sacc_out,
                                                unsigned int* __restrict__ counters,
                                                int s0, int P, int init)
{
    const int tid = blockIdx.x * 64 + threadIdx.x;
    const int b = tid >> 10, n = tid & (NOUT - 1);
    const int Tc = P * T;
    float v = init ? 0.f : vstate[tid];
    const float* ip = Iout + (size_t)b * Tc * NOUT + n;
    int cnt = 0;

    float cur[T];
    #pragma unroll
    for (int t = 0; t < T; ++t) cur[t] = ip[(size_t)t * NOUT];

    for (int sl = 0; sl < P; ++sl) {
        float nxt[T];
        const bool has = (sl + 1 < P);
        if (has) {
            const float* ip2 = ip + (size_t)(sl + 1) * T * NOUT;
            #pragma unroll
            for (int t = 0; t < T; ++t) nxt[t] = ip2[(size_t)t * NOUT];
        }
        float sacc = 0.f;
        #pragma unroll
        for (int t = 0; t < T; ++t) {
            v = __fadd_rn(__fmul_rn(0.9f, v), cur[t]);
            const bool sp = (v >= 1.0f);
            v = sp ? (v - 1.0f) : v;
            sacc += sp ? 1.f : 0.f;
            cnt += sp ? 1 : 0;
        }
        sacc_out[(size_t)(b*S + s0 + sl) * NOUT + n] = sacc;
        if (has) {
            #pragma unroll
            for (int t = 0; t < T; ++t) cur[t] = nxt[t];
        }
    }
    vstate[tid] = v;
    atomicAdd(counters + 1, (unsigned int)cnt);
}

__global__ void k_init(unsigned int* c)
{
    if (threadIdx.x < 2) c[threadIdx.x] = 0u;
}

__global__ void k_rate(const unsigned int* __restrict__ c, float* __restrict__ out)
{
    if (threadIdx.x == 0 && blockIdx.x == 0) {
        const float total = (float)c[0] + (float)c[1];
        out[0] = total / (float)(B * S * (NIN + NOUT) * T);
    }
}

// ---------------------------------------------------------------------------
extern "C" void kernel_launch(void* const* d_in, const int* in_sizes, int n_in,
                              void* d_out, int out_size, void* d_ws, size_t ws_size,
                              hipStream_t stream)
{
    const float* E    = (const float*)d_in[0];
    const float* Win  = (const float*)d_in[1];
    const float* bin  = (const float*)d_in[2];
    const float* Wc   = (const float*)d_in[3];
    const float* Wout = (const float*)d_in[4];
    const float* bout = (const float*)d_in[5];
    float* out = (float*)d_out;

    char* w = (char*)d_ws;
    float* snn              = (float*)(w);                          // 4 MB (later reused for WcT)
    unsigned short* WhT     = (unsigned short*)(w);                 // 2 MB (aliases snn, after lif_inA)
    unsigned short* WlT     = (unsigned short*)(w + (2 << 20));     // 2 MB
    unsigned long long* msk = (unsigned long long*)(w + (4 << 20)); // 4 MB
    float* sacc             = (float*)(w + (8 << 20));              // 4 MB
    unsigned int* sbits     = (unsigned int*)(w + (8 << 20));       // 4 MB (aliases sacc; dead before lif_out)
    float* vst              = (float*)(w + (12 << 20));             // 32 KB
    unsigned int* cnt       = (unsigned int*)(w + (12 << 20) + (64 << 10));
    float* Iout             = (float*)(w + (13 << 20));

    const size_t base = (size_t)13 << 20;
    const size_t avail = (ws_size > base) ? (ws_size - base) : 0;
    int P = 1;
    if      (avail >= (size_t)B * 128 * T * NOUT * 4) P = 128;
    else if (avail >= (size_t)B *  16 * T * NOUT * 4) P = 16;
    else if (avail >= (size_t)B *   4 * T * NOUT * 4) P = 4;

    k_init<<<1, 64, 0, stream>>>(cnt);

    dim3 g1(NIN / 64, (B * S) / 64);
    k_gemm<<<g1, 256, 0, stream>>>(E, Win, bin, snn, B * S, NIN, D, 1);

    k_lif_inA<<<128, 64, 0, stream>>>(snn, sbits, cnt);
    k_lif_inB<<<B * S, 256, 0, stream>>>(sbits, msk);

    // snn is dead now: build transposed hi/lo bf16 split of W_conn in its place
    dim3 gp(NIN / 64, NOUT / 64);
    k_prep<<<gp, 256, 0, stream>>>(Wc, WhT, WlT);

    for (int c = 0; c < S / P; ++c) {
        dim3 gc((B * P * T) / 256, NOUT / 64);
        k_conn_mfma<<<gc, 256, 0, stream>>>((const uint4*)msk, WhT, WlT, Iout, c * P, P);
        k_lif_out<<<128, 64, 0, stream>>>(Iout, vst, sacc, cnt, c * P, P, c == 0 ? 1 : 0);
    }

    dim3 g2(D / 64, (B * S) / 64);
    k_gemm<<<g2, 256, 0, stream>>>(sacc, Wout, bout, out, B * S, D, NOUT, 0);

    k_rate<<<1, 64, 0, stream>>>(cnt, out + (size_t)B * S * D);
}

// Round 21
// 421.791 us; speedup vs baseline: 1.0484x; 1.0137x over previous
//
#include <hip/hip_runtime.h>
#include <stdint.h>

#define B 8
#define S 128
#define D 512
#define NIN 1024
#define NOUT 1024
#define T 32

typedef __attribute__((ext_vector_type(8))) short short8;
typedef __attribute__((ext_vector_type(4))) float floatx4;

// direct global->LDS 16B copy (no VGPR round-trip, counted by vmcnt)
__device__ __forceinline__ void gload_lds16(const void* g, void* l)
{
    __builtin_amdgcn_global_load_lds(
        (const __attribute__((address_space(1))) unsigned int*)g,
        (__attribute__((address_space(3))) unsigned int*)l,
        16, 0, 0);
}

// ---------------------------------------------------------------------------
// Generic fp32 tiled GEMM (64x64 tile): C = maybe_relu(A @ Bm + bias).
// Used for gemm1 (grid 16x16 = 256 blocks, full fill).
// ---------------------------------------------------------------------------
__global__ __launch_bounds__(256) void k_gemm(const float* __restrict__ A,
                                              const float* __restrict__ Bm,
                                              const float* __restrict__ bias,
                                              float* __restrict__ C,
                                              int M, int N, int K, int relu)
{
    __shared__ float As[16][64];
    __shared__ float Bs[16][64];
    const int tid = threadIdx.x;
    const int bx = blockIdx.x, by = blockIdx.y;
    const int tx = tid & 15, ty = tid >> 4;
    const int ar = tid >> 2, ak = (tid & 3) << 2;
    const int bk = tid >> 4, bc = (tid & 15) << 2;
    float acc[4][4] = {{0.f,0.f,0.f,0.f},{0.f,0.f,0.f,0.f},
                       {0.f,0.f,0.f,0.f},{0.f,0.f,0.f,0.f}};
    float4 a4 = *(const float4*)(A + (size_t)(by*64 + ar)*K + ak);
    float4 b4 = *(const float4*)(Bm + (size_t)bk*N + bx*64 + bc);
    for (int k0 = 0; k0 < K; k0 += 16) {
        __syncthreads();
        As[ak+0][ar] = a4.x; As[ak+1][ar] = a4.y;
        As[ak+2][ar] = a4.z; As[ak+3][ar] = a4.w;
        *(float4*)&Bs[bk][bc] = b4;
        float4 na, nb;
        const bool has = (k0 + 16 < K);
        if (has) {
            na = *(const float4*)(A + (size_t)(by*64 + ar)*K + k0 + 16 + ak);
            nb = *(const float4*)(Bm + (size_t)(k0 + 16 + bk)*N + bx*64 + bc);
        }
        __syncthreads();
        #pragma unroll
        for (int kk = 0; kk < 16; ++kk) {
            float4 av = *(const float4*)&As[kk][ty << 2];
            float4 bv = *(const float4*)&Bs[kk][tx << 2];
            acc[0][0] = fmaf(av.x, bv.x, acc[0][0]);
            acc[0][1] = fmaf(av.x, bv.y, acc[0][1]);
            acc[0][2] = fmaf(av.x, bv.z, acc[0][2]);
            acc[0][3] = fmaf(av.x, bv.w, acc[0][3]);
            acc[1][0] = fmaf(av.y, bv.x, acc[1][0]);
            acc[1][1] = fmaf(av.y, bv.y, acc[1][1]);
            acc[1][2] = fmaf(av.y, bv.z, acc[1][2]);
            acc[1][3] = fmaf(av.y, bv.w, acc[1][3]);
            acc[2][0] = fmaf(av.z, bv.x, acc[2][0]);
            acc[2][1] = fmaf(av.z, bv.y, acc[2][1]);
            acc[2][2] = fmaf(av.z, bv.z, acc[2][2]);
            acc[2][3] = fmaf(av.z, bv.w, acc[2][3]);
            acc[3][0] = fmaf(av.w, bv.x, acc[3][0]);
            acc[3][1] = fmaf(av.w, bv.y, acc[3][1]);
            acc[3][2] = fmaf(av.w, bv.z, acc[3][2]);
            acc[3][3] = fmaf(av.w, bv.w, acc[3][3]);
        }
        if (has) { a4 = na; b4 = nb; }
    }
    const int row0 = by*64 + (ty << 2), col0 = bx*64 + (tx << 2);
    float4 bb = *(const float4*)(bias + col0);
    #pragma unroll
    for (int i = 0; i < 4; ++i) {
        float4 o;
        o.x = acc[i][0] + bb.x; o.y = acc[i][1] + bb.y;
        o.z = acc[i][2] + bb.z; o.w = acc[i][3] + bb.w;
        if (relu) {
            o.x = fmaxf(o.x, 0.f); o.y = fmaxf(o.y, 0.f);
            o.z = fmaxf(o.z, 0.f); o.w = fmaxf(o.w, 0.f);
        }
        *(float4*)(C + (size_t)(row0 + i)*N + col0) = o;
    }
}

// ---------------------------------------------------------------------------
// fp32 GEMM, 64x32 tile (R21 change): for gemm2 (M=1024, N=512) the 64x64
// kernel gives only 128 blocks = half the GPU idle (measured ~28 us, 24% of
// fp32 peak). 64x32 tiles -> grid (16,16) = 256 blocks, full fill. Per
// output element the K-iteration / FMA chain order is identical to k_gemm
// -> bit-identical result. Per thread: 4 rows x 2 cols.
// ---------------------------------------------------------------------------
__global__ __launch_bounds__(256) void k_gemm_n32(const float* __restrict__ A,
                                                  const float* __restrict__ Bm,
                                                  const float* __restrict__ bias,
                                                  float* __restrict__ C,
                                                  int M, int N, int K, int relu)
{
    __shared__ float As[16][64];
    __shared__ float Bs[16][32];
    const int tid = threadIdx.x;
    const int bx = blockIdx.x, by = blockIdx.y;
    const int tx = tid & 15, ty = tid >> 4;          // tx: col pair, ty: row quad
    const int ar = tid >> 2, ak = (tid & 3) << 2;    // A staging (as k_gemm)
    const int bk = tid >> 4, bc = (tid & 15) << 1;   // B staging: float2
    float acc[4][2] = {{0.f,0.f},{0.f,0.f},{0.f,0.f},{0.f,0.f}};
    float4 a4 = *(const float4*)(A + (size_t)(by*64 + ar)*K + ak);
    float2 b2 = *(const float2*)(Bm + (size_t)bk*N + bx*32 + bc);
    for (int k0 = 0; k0 < K; k0 += 16) {
        __syncthreads();
        As[ak+0][ar] = a4.x; As[ak+1][ar] = a4.y;
        As[ak+2][ar] = a4.z; As[ak+3][ar] = a4.w;
        *(float2*)&Bs[bk][bc] = b2;
        float4 na; float2 nb;
        const bool has = (k0 + 16 < K);
        if (has) {
            na = *(const float4*)(A + (size_t)(by*64 + ar)*K + k0 + 16 + ak);
            nb = *(const float2*)(Bm + (size_t)(k0 + 16 + bk)*N + bx*32 + bc);
        }
        __syncthreads();
        #pragma unroll
        for (int kk = 0; kk < 16; ++kk) {
            float4 av = *(const float4*)&As[kk][ty << 2];
            float2 bv = *(const float2*)&Bs[kk][tx << 1];
            acc[0][0] = fmaf(av.x, bv.x, acc[0][0]);
            acc[0][1] = fmaf(av.x, bv.y, acc[0][1]);
            acc[1][0] = fmaf(av.y, bv.x, acc[1][0]);
            acc[1][1] = fmaf(av.y, bv.y, acc[1][1]);
            acc[2][0] = fmaf(av.z, bv.x, acc[2][0]);
            acc[2][1] = fmaf(av.z, bv.y, acc[2][1]);
            acc[3][0] = fmaf(av.w, bv.x, acc[3][0]);
            acc[3][1] = fmaf(av.w, bv.y, acc[3][1]);
        }
        if (has) { a4 = na; b2 = nb; }
    }
    const int row0 = by*64 + (ty << 2), col0 = bx*32 + (tx << 1);
    float2 bb = *(const float2*)(bias + col0);
    #pragma unroll
    for (int i = 0; i < 4; ++i) {
        float2 o;
        o.x = acc[i][0] + bb.x; o.y = acc[i][1] + bb.y;
        if (relu) { o.x = fmaxf(o.x, 0.f); o.y = fmaxf(o.y, 0.f); }
        *(float2*)(C + (size_t)(row0 + i)*N + col0) = o;
    }
}

// ---------------------------------------------------------------------------
// Input LIF phase A — split form + depth-2 prefetch (R15/R20-measured).
// One chain/thread, 8192 threads over 128 CUs.
// ---------------------------------------------------------------------------
__global__ __launch_bounds__(64) void k_lif_inA(const float* __restrict__ snn,
                                                unsigned int* __restrict__ sbits,
                                                unsigned int* __restrict__ counters)
{
    const int tid = blockIdx.x * 64 + threadIdx.x;   // 0..8191
    const int b = tid >> 10, n = tid & (NIN - 1);
    const float* cur = snn + (size_t)(b * S) * NIN + n;
    float v = 0.f;
    int cnt = 0;
    float I   = cur[0];
    float In1 = (1 < S) ? cur[(size_t)1 * NIN] : 0.f;
    for (int s = 0; s < S; ++s) {
        const float In2 = (s + 2 < S) ? cur[(size_t)(s + 2) * NIN] : 0.f;
        unsigned int bits = 0u;
        #pragma unroll
        for (int t = 0; t < T; ++t) {
            v = __fadd_rn(__fmul_rn(0.9f, v), I);
            const bool sp = (v >= 1.0f);
            v = sp ? (v - 1.0f) : v;
            bits |= (sp ? 1u : 0u) << t;
        }
        sbits[(size_t)(b * S + s) * NIN + n] = bits;
        cnt += __popc(bits);
        I = In1; In1 = In2;
    }
    atomicAdd(counters, (unsigned int)cnt);
}

// ---------------------------------------------------------------------------
// Input LIF phase B — R3-exact: parallel rebuild of the u64 ballot masks.
// ---------------------------------------------------------------------------
__global__ __launch_bounds__(256) void k_lif_inB(const unsigned int* __restrict__ sbits,
                                                 unsigned long long* __restrict__ masks)
{
    const int bs = blockIdx.x;                 // b*S+s
    const int w = threadIdx.x >> 6, lane = threadIdx.x & 63;
    #pragma unroll
    for (int i = 0; i < 4; ++i) {
        const int wq = w * 4 + i;
        const unsigned int bits = sbits[(size_t)bs * NIN + wq * 64 + lane];
        #pragma unroll
        for (int t = 0; t < T; ++t) {
            const unsigned long long m = __ballot((bits >> t) & 1u);
            if (lane == 0)
                masks[((size_t)bs * T + t) * 16 + wq] = m;
        }
    }
}

// ---------------------------------------------------------------------------
// Prep: transpose W_conn [k][n] -> WcT [n][k] and split fp32 = bf16_hi+bf16_lo
// ---------------------------------------------------------------------------
__global__ __launch_bounds__(256) void k_prep(const float* __restrict__ Wc,
                                              unsigned short* __restrict__ WhT,
                                              unsigned short* __restrict__ WlT)
{
    __shared__ float tile[64][65];
    const int k0 = blockIdx.x * 64, n0 = blockIdx.y * 64;
    const int tx = threadIdx.x & 63, ty = threadIdx.x >> 6;
    #pragma unroll
    for (int p = 0; p < 16; ++p) {
        const int kl = p*4 + ty;
        tile[kl][tx] = Wc[(size_t)(k0 + kl) * NOUT + n0 + tx];
    }
    __syncthreads();
    #pragma unroll
    for (int p = 0; p < 16; ++p) {
        const int nl = p*4 + ty;
        const float w = tile[tx][nl];
        const unsigned int u  = __float_as_uint(w);
        const unsigned int hb = (u + 0x7FFFu + ((u >> 16) & 1u)) & 0xFFFF0000u; // bf16 RNE
        const float hif = __uint_as_float(hb);
        const float lo  = w - hif;                                             // exact
        const unsigned int ul = __float_as_uint(lo);
        const unsigned short lob = (unsigned short)((ul + 0x7FFFu + ((ul >> 16) & 1u)) >> 16);
        WhT[(size_t)(n0 + nl) * NIN + k0 + tx] = (unsigned short)(hb >> 16);
        WlT[(size_t)(n0 + nl) * NIN + k0 + tx] = lob;
    }
}

// ---------------------------------------------------------------------------
// Spike GEMM via MFMA — R15/R20-exact (122 us, twice-verified session best).
// Plateau documented across R3-R19: BK=64 (+12%), f=8 (+14%, VGPR cliff),
// launch-bounds cap (spill disaster), VALU A-frag (+12.5 us), kc-dbuf
// (compiler-folded), XCD remap (FETCH 2x, dur flat -> staging fully hidden).
// ---------------------------------------------------------------------------
__global__ __launch_bounds__(256) void k_conn_mfma(const uint4* __restrict__ masks128,
                                                   const unsigned short* __restrict__ WhT,
                                                   const unsigned short* __restrict__ WlT,
                                                   float* __restrict__ Iout,
                                                   int s0, int P)
{
    __shared__ uint4 lut[256];
    __shared__ unsigned short Bsm[2][2][64][128];   // [buf][mat][col][k] 64 KB

    const int tid = threadIdx.x;
    {
        const unsigned int bb = (unsigned int)tid;
        unsigned int r[4];
        #pragma unroll
        for (int i = 0; i < 4; ++i) {
            const unsigned int b0 = (bb >> (2*i)) & 1u, b1 = (bb >> (2*i+1)) & 1u;
            r[i] = (b0 ? 0x3F80u : 0u) | (b1 ? 0x3F800000u : 0u);
        }
        lut[tid] = make_uint4(r[0], r[1], r[2], r[3]);
    }

    const int w = tid >> 6, lane = tid & 63;
    const int r16 = lane & 15, q = lane >> 4;
    const int PT = P * T;
    const int rowblk = blockIdx.x * 256 + w * 64;
    const int cb = blockIdx.y * 64;

    const uint4* aptr[4];
    #pragma unroll
    for (int f = 0; f < 4; ++f) {
        const int r = rowblk + f*16 + r16;
        const int b = r / PT;
        const int within = r - b * PT;
        const int grow = (b * S + s0) * T + within;
        aptr[f] = masks128 + (size_t)grow * 8;
    }

    // per-thread staging sources (8 slots), with source-side XOR swizzle
    const unsigned short* stg_src[8];
    #pragma unroll
    for (int i = 0; i < 8; ++i) {
        const int flat = tid + i * 256;          // [mat(1)|col(6)|k16(4)]
        const int mat  = flat >> 10;
        const int col  = (flat >> 4) & 63;
        const int k16  = flat & 15;
        const int k16s = k16 ^ (col & 7);        // inverse swizzle on source
        stg_src[i] = (mat ? WlT : WhT) + (size_t)(cb + col) * NIN + k16s * 8;
    }

#define STAGE(BUF, CH) do {                                                   \
        char* dst0 = (char*)(&Bsm[BUF][0][0][0]) + (size_t)tid * 16;          \
        _Pragma("unroll")                                                     \
        for (int i_ = 0; i_ < 8; ++i_)                                        \
            gload_lds16(stg_src[i_] + (CH) * 128, dst0 + i_ * 4096);          \
    } while (0)

#define COMPUTE(BUF, AW) do {                                                 \
        _Pragma("unroll")                                                     \
        for (int kc = 0; kc < 4; ++kc) {                                      \
            short8 bh[4], bl[4];                                              \
            const int kread = ((kc*4 + q) ^ (r16 & 7)) * 8;                   \
            _Pragma("unroll")                                                 \
            for (int c = 0; c < 4; ++c) {                                     \
                bh[c] = *(const short8*)&Bsm[BUF][0][c*16 + r16][kread];      \
                bl[c] = *(const short8*)&Bsm[BUF][1][c*16 + r16][kread];      \
            }                                                                 \
            _Pragma("unroll")                                                 \
            for (int f = 0; f < 4; ++f) {                                     \
                const unsigned int word = (kc == 0) ? AW[f].x                 \
                                        : (kc == 1) ? AW[f].y                 \
                                        : (kc == 2) ? AW[f].z : AW[f].w;      \
                const unsigned int byte = (word >> (q * 8)) & 0xFFu;          \
                const short8 a = *(const short8*)&lut[byte];                  \
                _Pragma("unroll")                                             \
                for (int c = 0; c < 4; ++c) {                                 \
                    acc[f][c] = __builtin_amdgcn_mfma_f32_16x16x32_bf16(      \
                                    a, bh[c], acc[f][c], 0, 0, 0);            \
                    acc[f][c] = __builtin_amdgcn_mfma_f32_16x16x32_bf16(      \
                                    a, bl[c], acc[f][c], 0, 0, 0);            \
                }                                                             \
            }                                                                 \
        }                                                                     \
    } while (0)

    floatx4 acc[4][4];
    #pragma unroll
    for (int f = 0; f < 4; ++f)
        #pragma unroll
        for (int c = 0; c < 4; ++c)
            acc[f][c] = (floatx4){0.f, 0.f, 0.f, 0.f};

    uint4 awA[4], awB[4];
    #pragma unroll
    for (int f = 0; f < 4; ++f) awA[f] = aptr[f][0];
    STAGE(0, 0);
    __syncthreads();            // drains stage(0) + LUT writes

    #pragma unroll 1
    for (int ch = 0; ch < 8; ch += 2) {
        // phase A: buf0 holds chunk ch; prefetch ch+1 into buf1
        STAGE(1, ch + 1);
        #pragma unroll
        for (int f = 0; f < 4; ++f) awB[f] = aptr[f][ch + 1];
        COMPUTE(0, awA);
        __syncthreads();        // stage(ch+1) done (hidden under MFMAs)

        // phase B: buf1 holds chunk ch+1; prefetch ch+2 into buf0
        if (ch + 2 < 8) {
            STAGE(0, ch + 2);
            #pragma unroll
            for (int f = 0; f < 4; ++f) awA[f] = aptr[f][ch + 2];
        }
        COMPUTE(1, awB);
        __syncthreads();
    }
#undef STAGE
#undef COMPUTE

    #pragma unroll
    for (int f = 0; f < 4; ++f) {
        const int row = rowblk + f*16 + q*4;
        #pragma unroll
        for (int c = 0; c < 4; ++c) {
            const int col = cb + c*16 + r16;
            #pragma unroll
            for (int i = 0; i < 4; ++i)
                Iout[(size_t)(row + i) * NOUT + col] = acc[f][c][i];
        }
    }
}

// ---------------------------------------------------------------------------
// Output-population LIF, 128x64 grid, depth-1 prefetch (R15/R20-measured).
// ---------------------------------------------------------------------------
__global__ __launch_bounds__(64) void k_lif_out(const float* __restrict__ Iout,
                                                float* __restrict__ vstate,
                                                float* __restrict__ sacc_out,
                                                unsigned int* __restrict__ counters,
                                                int s0, int P, int init)
{
    const int tid = blockIdx.x * 64 + threadIdx.x;
    const int b = tid >> 10, n = tid & (NOUT - 1);
    const int Tc = P * T;
    float v = init ? 0.f : vstate[tid];
    const float* ip = Iout + (size_t)b * Tc * NOUT + n;
    int cnt = 0;

    float cur[T];
    #pragma unroll
    for (int t = 0; t < T; ++t) cur[t] = ip[(size_t)t * NOUT];

    for (int sl = 0; sl < P; ++sl) {
        float nxt[T];
        const bool has = (sl + 1 < P);
        if (has) {
            const float* ip2 = ip + (size_t)(sl + 1) * T * NOUT;
            #pragma unroll
            for (int t = 0; t < T; ++t) nxt[t] = ip2[(size_t)t * NOUT];
        }
        float sacc = 0.f;
        #pragma unroll
        for (int t = 0; t < T; ++t) {
            v = __fadd_rn(__fmul_rn(0.9f, v), cur[t]);
            const bool sp = (v >= 1.0f);
            v = sp ? (v - 1.0f) : v;
            sacc += sp ? 1.f : 0.f;
            cnt += sp ? 1 : 0;
        }
        sacc_out[(size_t)(b*S + s0 + sl) * NOUT + n] = sacc;
        if (has) {
            #pragma unroll
            for (int t = 0; t < T; ++t) cur[t] = nxt[t];
        }
    }
    vstate[tid] = v;
    atomicAdd(counters + 1, (unsigned int)cnt);
}

__global__ void k_init(unsigned int* c)
{
    if (threadIdx.x < 2) c[threadIdx.x] = 0u;
}

__global__ void k_rate(const unsigned int* __restrict__ c, float* __restrict__ out)
{
    if (threadIdx.x == 0 && blockIdx.x == 0) {
        const float total = (float)c[0] + (float)c[1];
        out[0] = total / (float)(B * S * (NIN + NOUT) * T);
    }
}

// ---------------------------------------------------------------------------
extern "C" void kernel_launch(void* const* d_in, const int* in_sizes, int n_in,
                              void* d_out, int out_size, void* d_ws, size_t ws_size,
                              hipStream_t stream)
{
    const float* E    = (const float*)d_in[0];
    const float* Win  = (const float*)d_in[1];
    const float* bin  = (const float*)d_in[2];
    const float* Wc   = (const float*)d_in[3];
    const float* Wout = (const float*)d_in[4];
    const float* bout = (const float*)d_in[5];
    float* out = (float*)d_out;

    char* w = (char*)d_ws;
    float* snn              = (float*)(w);                          // 4 MB (later reused for WcT)
    unsigned short* WhT     = (unsigned short*)(w);                 // 2 MB (aliases snn, after lif_inA)
    unsigned short* WlT     = (unsigned short*)(w + (2 << 20));     // 2 MB
    unsigned long long* msk = (unsigned long long*)(w + (4 << 20)); // 4 MB
    float* sacc             = (float*)(w + (8 << 20));              // 4 MB
    unsigned int* sbits     = (unsigned int*)(w + (8 << 20));       // 4 MB (aliases sacc; dead before lif_out)
    float* vst              = (float*)(w + (12 << 20));             // 32 KB
    unsigned int* cnt       = (unsigned int*)(w + (12 << 20) + (64 << 10));
    float* Iout             = (float*)(w + (13 << 20));

    const size_t base = (size_t)13 << 20;
    const size_t avail = (ws_size > base) ? (ws_size - base) : 0;
    int P = 1;
    if      (avail >= (size_t)B * 128 * T * NOUT * 4) P = 128;
    else if (avail >= (size_t)B *  16 * T * NOUT * 4) P = 16;
    else if (avail >= (size_t)B *   4 * T * NOUT * 4) P = 4;

    k_init<<<1, 64, 0, stream>>>(cnt);

    dim3 g1(NIN / 64, (B * S) / 64);
    k_gemm<<<g1, 256, 0, stream>>>(E, Win, bin, snn, B * S, NIN, D, 1);

    k_lif_inA<<<128, 64, 0, stream>>>(snn, sbits, cnt);
    k_lif_inB<<<B * S, 256, 0, stream>>>(sbits, msk);

    // snn is dead now: build transposed hi/lo bf16 split of W_conn in its place
    dim3 gp(NIN / 64, NOUT / 64);
    k_prep<<<gp, 256, 0, stream>>>(Wc, WhT, WlT);

    for (int c = 0; c < S / P; ++c) {
        dim3 gc((B * P * T) / 256, NOUT / 64);
        k_conn_mfma<<<gc, 256, 0, stream>>>((const uint4*)msk, WhT, WlT, Iout, c * P, P);
        k_lif_out<<<128, 64, 0, stream>>>(Iout, vst, sacc, cnt, c * P, P, c == 0 ? 1 : 0);
    }

    // final GEMM: 64x32 tiles -> 256 blocks (full CU fill; was 128)
    dim3 g2(D / 32, (B * S) / 64);
    k_gemm_n32<<<g2, 256, 0, stream>>>(sacc, Wout, bout, out, B * S, D, NOUT, 0);

    k_rate<<<1, 64, 0, stream>>>(cnt, out + (size_t)B * S * D);
}